// Round 6
// baseline (81.589 us; speedup 1.0000x reference)
//
#include <hip/hip_runtime.h>

#define N_NODES 10000
#define IN_DIM  256
#define OUT_DIM 64
#define ALPHA   0.2f
#define CAPS    128   // slot capacity/row (mean deg 32, max ~66; P(>128) ~ 1e-40, clamped)
#define CAP     256   // CSR-fallback LDS edge capacity

// ---------------------------------------------------------------------------
// Kernel 1: Wh = X @ W (10000x256 @ 256x64) + scores es/ed.
// Round-5 lesson: VMEM-path W reads made the GEMM L1-BW-bound (~16B of W
// traffic per FMA*wave). Fix: stage W (64KB) in LDS ONCE per block, read
// W[k][lane] as ds_read_b32 (256B/wave span -> 2-way bank alias = free);
// X via wave-uniform scalar loads (readfirstlane'd wave id). 8 rows/wave ->
// per kk-step: 4 ds_read + 8 uniform float4 + 32 FMA (VALU-bound, as ideal).
// Also zeroes cur[] for k_fill_slots (saves a fill dispatch).
// Round-3 lesson: do NOT fuse phases with grid.sync() (69us -> 240us).
// ---------------------------------------------------------------------------
__global__ __launch_bounds__(256) void k_gemm(const float* __restrict__ X,
                                              const float* __restrict__ W,
                                              const float* __restrict__ a,
                                              float* __restrict__ Wh,
                                              float* __restrict__ es,
                                              float* __restrict__ ed,
                                              int* __restrict__ zero10k) {
    const int t = threadIdx.x;
    const int gid = blockIdx.x * 256 + t;
    if (gid < N_NODES) zero10k[gid] = 0;

    __shared__ float wlds[IN_DIM][OUT_DIM];   // 64 KB, staged once
    for (int i = t; i < IN_DIM * OUT_DIM / 4; i += 256)
        ((float4*)wlds)[i] = ((const float4*)W)[i];
    __syncthreads();

    const int wave = __builtin_amdgcn_readfirstlane(t >> 6);  // wave-uniform SGPR
    const int lane = t & 63;
    const int row0 = blockIdx.x * 32 + wave * 8;              // 313 blocks x 32 rows

    // clamped row pointers (loads always in-bounds; stores guarded below)
    const float* xp[8];
#pragma unroll
    for (int r = 0; r < 8; ++r) {
        int row = row0 + r;
        if (row > N_NODES - 1) row = N_NODES - 1;
        xp[r] = X + (size_t)row * IN_DIM;
    }

    float acc[8] = {0.f, 0.f, 0.f, 0.f, 0.f, 0.f, 0.f, 0.f};

    for (int kk = 0; kk < IN_DIM; kk += 4) {
        float w0 = wlds[kk + 0][lane];   // ds_read_b32, conflict-free (2-way)
        float w1 = wlds[kk + 1][lane];
        float w2 = wlds[kk + 2][lane];
        float w3 = wlds[kk + 3][lane];
#pragma unroll
        for (int r = 0; r < 8; ++r) {
            float4 xv = *(const float4*)(xp[r] + kk);   // wave-uniform (scalarizable)
            acc[r] = fmaf(xv.x, w0, acc[r]);
            acc[r] = fmaf(xv.y, w1, acc[r]);
            acc[r] = fmaf(xv.z, w2, acc[r]);
            acc[r] = fmaf(xv.w, w3, acc[r]);
        }
    }

    const float asrc = a[lane];
    const float adst = a[OUT_DIM + lane];
#pragma unroll
    for (int r = 0; r < 8; ++r) {
        int row = row0 + r;
        if (row < N_NODES) {
            float v = acc[r];
            Wh[(size_t)row * OUT_DIM + lane] = v;
            float s1 = v * asrc, s2 = v * adst;
#pragma unroll
            for (int o = 32; o > 0; o >>= 1) {
                s1 += __shfl_xor(s1, o, 64);
                s2 += __shfl_xor(s2, o, 64);
            }
            if (lane == 0) { es[row] = s1; ed[row] = s2; }
        }
    }
}

// ---------------------------------------------------------------------------
// Kernel 2: scatter edges into fixed-stride per-row buckets, storing the
// FINISHED score {dst, e = leakyrelu(es[s]+ed[d])}. es/ed 40KB, cache-resident.
// ---------------------------------------------------------------------------
__global__ void k_fill_slots(const int* __restrict__ src, const int* __restrict__ dst,
                             int E, const float* __restrict__ es,
                             const float* __restrict__ ed,
                             int* __restrict__ cur, int2* __restrict__ slots) {
    int i = blockIdx.x * 256 + threadIdx.x;
    if (i < E) {
        int s = src[i], d = dst[i];
        float e = es[s] + ed[d];
        e = e > 0.f ? e : ALPHA * e;
        int p = atomicAdd(&cur[s], 1);
        if (p < CAPS) slots[(size_t)s * CAPS + p] = make_int2(d, __float_as_int(e));
    }
}

// ---------------------------------------------------------------------------
// Kernel 3: one wave per row. Dedupe duplicate (src,dst) pairs (reference
// .at[].set counts each unique pair ONCE; duplicate e identical), softmax,
// h' = sum p_i/S * Wh[dst_i,:]. lane = out dim -> 256B coalesced Wh gathers.
// ---------------------------------------------------------------------------
__global__ __launch_bounds__(64) void k_attn_slots(const int* __restrict__ cur,
                                                   const int2* __restrict__ slots,
                                                   const float* __restrict__ Wh,
                                                   float* __restrict__ out) {
    const int r = blockIdx.x;
    const int lane = threadIdx.x;
    int deg = cur[r];
    if (deg > CAPS) deg = CAPS;

    if (deg == 0) {
        // softmax of all-NEG_FILL row is uniform -> column mean of Wh
        float acc = 0.f;
        for (int j = 0; j < N_NODES; ++j) acc += Wh[(size_t)j * OUT_DIM + lane];
        out[(size_t)r * OUT_DIM + lane] = acc / (float)N_NODES;
        return;
    }

    __shared__ int   sdst[CAPS];
    __shared__ float sp[CAPS];

    // pass A: load finished slot pairs
    for (int i = lane; i < deg; i += 64) {
        int2 v = slots[(size_t)r * CAPS + i];
        sdst[i] = v.x;
        sp[i]   = __int_as_float(v.y);
    }
    __syncthreads();

    // pass B: dedupe-mark + row max
    float m = -INFINITY;
    for (int i = lane; i < deg; i += 64) {
        int d = sdst[i];
        bool first = true;
        for (int j = 0; j < i; ++j)
            if (sdst[j] == d) { first = false; break; }
        if (first) m = fmaxf(m, sp[i]);
        else       sp[i] = -INFINITY;     // exp() -> 0
    }
#pragma unroll
    for (int o = 32; o > 0; o >>= 1) m = fmaxf(m, __shfl_xor(m, o, 64));
    __syncthreads();

    // pass C: exp + sum
    float ssum = 0.f;
    for (int i = lane; i < deg; i += 64) {
        float p = __expf(sp[i] - m);
        sp[i] = p;
        ssum += p;
    }
#pragma unroll
    for (int o = 32; o > 0; o >>= 1) ssum += __shfl_xor(ssum, o, 64);
    __syncthreads();

    // pass D: accumulate h', 4 gathers in flight
    float acc = 0.f;
    int i = 0;
    for (; i + 4 <= deg; i += 4) {
        float p0 = sp[i + 0], p1 = sp[i + 1], p2 = sp[i + 2], p3 = sp[i + 3];
        int   q0 = sdst[i + 0], q1 = sdst[i + 1], q2 = sdst[i + 2], q3 = sdst[i + 3];
        float w0 = Wh[(size_t)q0 * OUT_DIM + lane];
        float w1 = Wh[(size_t)q1 * OUT_DIM + lane];
        float w2 = Wh[(size_t)q2 * OUT_DIM + lane];
        float w3 = Wh[(size_t)q3 * OUT_DIM + lane];
        acc = fmaf(p0, w0, acc);
        acc = fmaf(p1, w1, acc);
        acc = fmaf(p2, w2, acc);
        acc = fmaf(p3, w3, acc);
    }
    for (; i < deg; ++i)
        acc = fmaf(sp[i], Wh[(size_t)sdst[i] * OUT_DIM + lane], acc);

    out[(size_t)r * OUT_DIM + lane] = acc / ssum;
}

// ---------------------------------------------------------------------------
// CSR FALLBACK (only if ws can't hold the slot buckets).
// ---------------------------------------------------------------------------
__global__ void k_count(const int* __restrict__ src, int E, int* __restrict__ cnt) {
    int i = blockIdx.x * 256 + threadIdx.x;
    if (i < E) atomicAdd(&cnt[src[i]], 1);
}

__global__ __launch_bounds__(1024) void k_scan(const int* __restrict__ cnt,
                                               int* __restrict__ off,
                                               int* __restrict__ cur,
                                               int n, int E) {
    __shared__ int part[1024];
    const int t = threadIdx.x;
    const int CH = (N_NODES + 1023) / 1024;
    int beg = t * CH, end = min(beg + CH, n);
    int s = 0;
    for (int i = beg; i < end; ++i) s += cnt[i];
    part[t] = s;
    __syncthreads();
    for (int d = 1; d < 1024; d <<= 1) {
        int v = (t >= d) ? part[t - d] : 0;
        __syncthreads();
        part[t] += v;
        __syncthreads();
    }
    int run = (t == 0) ? 0 : part[t - 1];
    for (int i = beg; i < end; ++i) {
        off[i] = run;
        cur[i] = run;
        run += cnt[i];
    }
    if (t == 0) off[n] = E;
}

__global__ void k_fill(const int* __restrict__ src, const int* __restrict__ dst, int E,
                       int* __restrict__ cur, int* __restrict__ csr) {
    int i = blockIdx.x * 256 + threadIdx.x;
    if (i < E) {
        int p = atomicAdd(&cur[src[i]], 1);
        csr[p] = dst[i];
    }
}

__global__ __launch_bounds__(64) void k_attn(const int* __restrict__ off,
                                             const int* __restrict__ csr,
                                             const float* __restrict__ es,
                                             const float* __restrict__ ed,
                                             const float* __restrict__ Wh,
                                             float* __restrict__ out) {
    const int r = blockIdx.x;
    const int lane = threadIdx.x;
    const int beg = off[r];
    const int deg = off[r + 1] - beg;
    if (deg == 0) {
        float acc = 0.f;
        for (int j = 0; j < N_NODES; ++j) acc += Wh[(size_t)j * OUT_DIM + lane];
        out[(size_t)r * OUT_DIM + lane] = acc / (float)N_NODES;
        return;
    }
    const float er = es[r];
    __shared__ int   sdst[CAP];
    __shared__ float sp[CAP];
    if (deg <= CAP) {
        for (int i = lane; i < deg; i += 64) sdst[i] = csr[beg + i];
        __syncthreads();
        float m = -INFINITY;
        for (int i = lane; i < deg; i += 64) {
            int d = sdst[i];
            bool first = true;
            for (int j = 0; j < i; ++j)
                if (sdst[j] == d) { first = false; break; }
            float e;
            if (first) {
                e = er + ed[d];
                e = e > 0.f ? e : ALPHA * e;
                m = fmaxf(m, e);
            } else e = -INFINITY;
            sp[i] = e;
        }
#pragma unroll
        for (int o = 32; o > 0; o >>= 1) m = fmaxf(m, __shfl_xor(m, o, 64));
        __syncthreads();
        float ssum = 0.f;
        for (int i = lane; i < deg; i += 64) {
            float p = __expf(sp[i] - m);
            sp[i] = p;
            ssum += p;
        }
#pragma unroll
        for (int o = 32; o > 0; o >>= 1) ssum += __shfl_xor(ssum, o, 64);
        __syncthreads();
        float acc = 0.f;
        for (int i = 0; i < deg; ++i)
            acc = fmaf(sp[i], Wh[(size_t)sdst[i] * OUT_DIM + lane], acc);
        out[(size_t)r * OUT_DIM + lane] = acc / ssum;
    } else {
        float m = -INFINITY;
        for (int i = lane; i < deg; i += 64) {
            int d = csr[beg + i];
            bool first = true;
            for (int j = 0; j < i; ++j)
                if (csr[beg + j] == d) { first = false; break; }
            if (first) {
                float e = er + ed[d];
                e = e > 0.f ? e : ALPHA * e;
                m = fmaxf(m, e);
            }
        }
#pragma unroll
        for (int o = 32; o > 0; o >>= 1) m = fmaxf(m, __shfl_xor(m, o, 64));
        float ssum = 0.f;
        for (int i = lane; i < deg; i += 64) {
            int d = csr[beg + i];
            bool first = true;
            for (int j = 0; j < i; ++j)
                if (csr[beg + j] == d) { first = false; break; }
            if (first) {
                float e = er + ed[d];
                e = e > 0.f ? e : ALPHA * e;
                ssum += __expf(e - m);
            }
        }
#pragma unroll
        for (int o = 32; o > 0; o >>= 1) ssum += __shfl_xor(ssum, o, 64);
        float acc = 0.f;
        for (int i = 0; i < deg; ++i) {
            int d = csr[beg + i];
            bool first = true;
            for (int j = 0; j < i; ++j)
                if (csr[beg + j] == d) { first = false; break; }
            if (first) {
                float e = er + ed[d];
                e = e > 0.f ? e : ALPHA * e;
                acc = fmaf(__expf(e - m), Wh[(size_t)d * OUT_DIM + lane], acc);
            }
        }
        out[(size_t)r * OUT_DIM + lane] = acc / ssum;
    }
}

// ---------------------------------------------------------------------------
extern "C" void kernel_launch(void* const* d_in, const int* in_sizes, int n_in,
                              void* d_out, int out_size, void* d_ws, size_t ws_size,
                              hipStream_t stream) {
    const float* X     = (const float*)d_in[0];
    const int*   edges = (const int*)d_in[1];
    const float* W     = (const float*)d_in[2];
    const float* a     = (const float*)d_in[3];
    float* out = (float*)d_out;

    const int E = in_sizes[1] / 2;
    const int* src = edges;
    const int* dst = edges + E;

    char* ws = (char*)d_ws;
    size_t o = 0;
    auto carve = [&](size_t bytes) -> void* {
        o = (o + 255) & ~(size_t)255;
        void* p = ws + o;
        o += bytes;
        return p;
    };
    float* Wh  = (float*)carve((size_t)N_NODES * OUT_DIM * 4);
    float* es  = (float*)carve((size_t)N_NODES * 4);
    float* ed  = (float*)carve((size_t)N_NODES * 4);
    int*   cur = (int*)carve((size_t)N_NODES * 4);

    size_t slots_off = (o + 255) & ~(size_t)255;
    size_t need_fast = slots_off + (size_t)N_NODES * CAPS * 8;

    if (ws_size >= need_fast) {
        int2* slots = (int2*)(ws + slots_off);
        k_gemm      <<<313, 256, 0, stream>>>(X, W, a, Wh, es, ed, cur);
        k_fill_slots<<<(E + 255) / 256, 256, 0, stream>>>(src, dst, E, es, ed, cur, slots);
        k_attn_slots<<<N_NODES, 64, 0, stream>>>(cur, slots, Wh, out);
    } else {
        int* cnt = (int*)carve((size_t)N_NODES * 4);
        int* off = (int*)carve((size_t)(N_NODES + 1) * 4);
        int* csr = (int*)carve((size_t)E * 4);
        k_gemm <<<313, 256, 0, stream>>>(X, W, a, Wh, es, ed, cnt);
        k_count<<<(E + 255) / 256, 256, 0, stream>>>(src, E, cnt);
        k_scan <<<1, 1024, 0, stream>>>(cnt, off, cur, N_NODES, E);
        k_fill <<<(E + 255) / 256, 256, 0, stream>>>(src, dst, E, cur, csr);
        k_attn <<<N_NODES, 64, 0, stream>>>(off, csr, es, ed, Wh, out);
    }
}

// Round 7
// 80.644 us; speedup vs baseline: 1.0117x; 1.0117x over previous
//
#include <hip/hip_runtime.h>

#define N_NODES 10000
#define IN_DIM  256
#define OUT_DIM 64
#define ALPHA   0.2f
#define CAPS    128   // slot capacity/row (mean deg 32, max ~66; P(>128) ~ 1e-40, clamped)
#define CAP     256   // CSR-fallback LDS edge capacity

// ---------------------------------------------------------------------------
// Kernel 1: Wh = X @ W (10000x256 @ 256x64) + scores es/ed.
// Round-6 lesson: EVERY slow gemm variant was latency-bound (VALUBusy ~6%,
// Occ ~11%). 64KB W-in-LDS killed occupancy (2 blk/CU). Fix = maximize
// latency hiding: NO LDS, 2 rows/wave x 1250 blocks (~19 waves/CU), unroll 4
// so ~24 independent VMEM loads sit in flight per wave. X read as uniform
// dwordx4 (each 64B line feeds 4 consecutive k-steps -> 3/4 are L1 hits);
// W per-lane 256B coalesced, L1-resident. VALU floor ~2.1us, HBM X ~1.6us.
// Also zeroes cur[] for k_fill_slots (saves a fill dispatch).
// Round-3 lesson: do NOT fuse phases with grid.sync() (69us -> 240us).
// ---------------------------------------------------------------------------
__global__ __launch_bounds__(256) void k_gemm(const float* __restrict__ X,
                                              const float* __restrict__ W,
                                              const float* __restrict__ a,
                                              float* __restrict__ Wh,
                                              float* __restrict__ es,
                                              float* __restrict__ ed,
                                              int* __restrict__ zero10k) {
    const int t = threadIdx.x;
    const int gid = blockIdx.x * 256 + t;
    if (gid < N_NODES) zero10k[gid] = 0;

    const int wave = t >> 6, lane = t & 63;
    const int row0 = blockIdx.x * 8 + wave * 2;    // 1250 blocks x 8 rows = 10000

    const float* __restrict__ x0 = X + (size_t)(row0 + 0) * IN_DIM;
    const float* __restrict__ x1 = X + (size_t)(row0 + 1) * IN_DIM;

    float acc0 = 0.f, acc1 = 0.f;

#pragma unroll 4
    for (int kk = 0; kk < IN_DIM; kk += 4) {
        // per-lane W column loads, 256B coalesced, L1-resident
        float w0 = W[(kk + 0) * OUT_DIM + lane];
        float w1 = W[(kk + 1) * OUT_DIM + lane];
        float w2 = W[(kk + 2) * OUT_DIM + lane];
        float w3 = W[(kk + 3) * OUT_DIM + lane];
        // uniform X loads (same 64B line serves 4 k-steps)
        float4 xa = *(const float4*)(x0 + kk);
        float4 xb = *(const float4*)(x1 + kk);

        acc0 = fmaf(xa.x, w0, acc0); acc0 = fmaf(xa.y, w1, acc0);
        acc0 = fmaf(xa.z, w2, acc0); acc0 = fmaf(xa.w, w3, acc0);
        acc1 = fmaf(xb.x, w0, acc1); acc1 = fmaf(xb.y, w1, acc1);
        acc1 = fmaf(xb.z, w2, acc1); acc1 = fmaf(xb.w, w3, acc1);
    }

    const float asrc = a[lane];
    const float adst = a[OUT_DIM + lane];
    float accs[2] = {acc0, acc1};
#pragma unroll
    for (int r = 0; r < 2; ++r) {
        int row = row0 + r;
        float v = accs[r];
        Wh[(size_t)row * OUT_DIM + lane] = v;
        float s1 = v * asrc, s2 = v * adst;
#pragma unroll
        for (int o = 32; o > 0; o >>= 1) {
            s1 += __shfl_xor(s1, o, 64);
            s2 += __shfl_xor(s2, o, 64);
        }
        if (lane == 0) { es[row] = s1; ed[row] = s2; }
    }
}

// ---------------------------------------------------------------------------
// Kernel 2: scatter edges into fixed-stride per-row buckets, storing the
// FINISHED score {dst, e = leakyrelu(es[s]+ed[d])}. es/ed 40KB, cache-resident.
// ---------------------------------------------------------------------------
__global__ void k_fill_slots(const int* __restrict__ src, const int* __restrict__ dst,
                             int E, const float* __restrict__ es,
                             const float* __restrict__ ed,
                             int* __restrict__ cur, int2* __restrict__ slots) {
    int i = blockIdx.x * 256 + threadIdx.x;
    if (i < E) {
        int s = src[i], d = dst[i];
        float e = es[s] + ed[d];
        e = e > 0.f ? e : ALPHA * e;
        int p = atomicAdd(&cur[s], 1);
        if (p < CAPS) slots[(size_t)s * CAPS + p] = make_int2(d, __float_as_int(e));
    }
}

// ---------------------------------------------------------------------------
// Kernel 3: one wave per row. Dedupe duplicate (src,dst) pairs (reference
// .at[].set counts each unique pair ONCE; duplicate e identical), softmax,
// h' = sum p_i/S * Wh[dst_i,:]. lane = out dim -> 256B coalesced Wh gathers.
// ---------------------------------------------------------------------------
__global__ __launch_bounds__(64) void k_attn_slots(const int* __restrict__ cur,
                                                   const int2* __restrict__ slots,
                                                   const float* __restrict__ Wh,
                                                   float* __restrict__ out) {
    const int r = blockIdx.x;
    const int lane = threadIdx.x;
    int deg = cur[r];
    if (deg > CAPS) deg = CAPS;

    if (deg == 0) {
        // softmax of all-NEG_FILL row is uniform -> column mean of Wh
        float acc = 0.f;
        for (int j = 0; j < N_NODES; ++j) acc += Wh[(size_t)j * OUT_DIM + lane];
        out[(size_t)r * OUT_DIM + lane] = acc / (float)N_NODES;
        return;
    }

    __shared__ int   sdst[CAPS];
    __shared__ float sp[CAPS];

    // pass A: load finished slot pairs
    for (int i = lane; i < deg; i += 64) {
        int2 v = slots[(size_t)r * CAPS + i];
        sdst[i] = v.x;
        sp[i]   = __int_as_float(v.y);
    }
    __syncthreads();

    // pass B: dedupe-mark + row max
    float m = -INFINITY;
    for (int i = lane; i < deg; i += 64) {
        int d = sdst[i];
        bool first = true;
        for (int j = 0; j < i; ++j)
            if (sdst[j] == d) { first = false; break; }
        if (first) m = fmaxf(m, sp[i]);
        else       sp[i] = -INFINITY;     // exp() -> 0
    }
#pragma unroll
    for (int o = 32; o > 0; o >>= 1) m = fmaxf(m, __shfl_xor(m, o, 64));
    __syncthreads();

    // pass C: exp + sum
    float ssum = 0.f;
    for (int i = lane; i < deg; i += 64) {
        float p = __expf(sp[i] - m);
        sp[i] = p;
        ssum += p;
    }
#pragma unroll
    for (int o = 32; o > 0; o >>= 1) ssum += __shfl_xor(ssum, o, 64);
    __syncthreads();

    // pass D: accumulate h', 4 gathers in flight
    float acc = 0.f;
    int i = 0;
    for (; i + 4 <= deg; i += 4) {
        float p0 = sp[i + 0], p1 = sp[i + 1], p2 = sp[i + 2], p3 = sp[i + 3];
        int   q0 = sdst[i + 0], q1 = sdst[i + 1], q2 = sdst[i + 2], q3 = sdst[i + 3];
        float w0 = Wh[(size_t)q0 * OUT_DIM + lane];
        float w1 = Wh[(size_t)q1 * OUT_DIM + lane];
        float w2 = Wh[(size_t)q2 * OUT_DIM + lane];
        float w3 = Wh[(size_t)q3 * OUT_DIM + lane];
        acc = fmaf(p0, w0, acc);
        acc = fmaf(p1, w1, acc);
        acc = fmaf(p2, w2, acc);
        acc = fmaf(p3, w3, acc);
    }
    for (; i < deg; ++i)
        acc = fmaf(sp[i], Wh[(size_t)sdst[i] * OUT_DIM + lane], acc);

    out[(size_t)r * OUT_DIM + lane] = acc / ssum;
}

// ---------------------------------------------------------------------------
// CSR FALLBACK (only if ws can't hold the slot buckets).
// ---------------------------------------------------------------------------
__global__ void k_count(const int* __restrict__ src, int E, int* __restrict__ cnt) {
    int i = blockIdx.x * 256 + threadIdx.x;
    if (i < E) atomicAdd(&cnt[src[i]], 1);
}

__global__ __launch_bounds__(1024) void k_scan(const int* __restrict__ cnt,
                                               int* __restrict__ off,
                                               int* __restrict__ cur,
                                               int n, int E) {
    __shared__ int part[1024];
    const int t = threadIdx.x;
    const int CH = (N_NODES + 1023) / 1024;
    int beg = t * CH, end = min(beg + CH, n);
    int s = 0;
    for (int i = beg; i < end; ++i) s += cnt[i];
    part[t] = s;
    __syncthreads();
    for (int d = 1; d < 1024; d <<= 1) {
        int v = (t >= d) ? part[t - d] : 0;
        __syncthreads();
        part[t] += v;
        __syncthreads();
    }
    int run = (t == 0) ? 0 : part[t - 1];
    for (int i = beg; i < end; ++i) {
        off[i] = run;
        cur[i] = run;
        run += cnt[i];
    }
    if (t == 0) off[n] = E;
}

__global__ void k_fill(const int* __restrict__ src, const int* __restrict__ dst, int E,
                       int* __restrict__ cur, int* __restrict__ csr) {
    int i = blockIdx.x * 256 + threadIdx.x;
    if (i < E) {
        int p = atomicAdd(&cur[src[i]], 1);
        csr[p] = dst[i];
    }
}

__global__ __launch_bounds__(64) void k_attn(const int* __restrict__ off,
                                             const int* __restrict__ csr,
                                             const float* __restrict__ es,
                                             const float* __restrict__ ed,
                                             const float* __restrict__ Wh,
                                             float* __restrict__ out) {
    const int r = blockIdx.x;
    const int lane = threadIdx.x;
    const int beg = off[r];
    const int deg = off[r + 1] - beg;
    if (deg == 0) {
        float acc = 0.f;
        for (int j = 0; j < N_NODES; ++j) acc += Wh[(size_t)j * OUT_DIM + lane];
        out[(size_t)r * OUT_DIM + lane] = acc / (float)N_NODES;
        return;
    }
    const float er = es[r];
    __shared__ int   sdst[CAP];
    __shared__ float sp[CAP];
    if (deg <= CAP) {
        for (int i = lane; i < deg; i += 64) sdst[i] = csr[beg + i];
        __syncthreads();
        float m = -INFINITY;
        for (int i = lane; i < deg; i += 64) {
            int d = sdst[i];
            bool first = true;
            for (int j = 0; j < i; ++j)
                if (sdst[j] == d) { first = false; break; }
            float e;
            if (first) {
                e = er + ed[d];
                e = e > 0.f ? e : ALPHA * e;
                m = fmaxf(m, e);
            } else e = -INFINITY;
            sp[i] = e;
        }
#pragma unroll
        for (int o = 32; o > 0; o >>= 1) m = fmaxf(m, __shfl_xor(m, o, 64));
        __syncthreads();
        float ssum = 0.f;
        for (int i = lane; i < deg; i += 64) {
            float p = __expf(sp[i] - m);
            sp[i] = p;
            ssum += p;
        }
#pragma unroll
        for (int o = 32; o > 0; o >>= 1) ssum += __shfl_xor(ssum, o, 64);
        __syncthreads();
        float acc = 0.f;
        for (int i = 0; i < deg; ++i)
            acc = fmaf(sp[i], Wh[(size_t)sdst[i] * OUT_DIM + lane], acc);
        out[(size_t)r * OUT_DIM + lane] = acc / ssum;
    } else {
        float m = -INFINITY;
        for (int i = lane; i < deg; i += 64) {
            int d = csr[beg + i];
            bool first = true;
            for (int j = 0; j < i; ++j)
                if (csr[beg + j] == d) { first = false; break; }
            if (first) {
                float e = er + ed[d];
                e = e > 0.f ? e : ALPHA * e;
                m = fmaxf(m, e);
            }
        }
#pragma unroll
        for (int o = 32; o > 0; o >>= 1) m = fmaxf(m, __shfl_xor(m, o, 64));
        float ssum = 0.f;
        for (int i = lane; i < deg; i += 64) {
            int d = csr[beg + i];
            bool first = true;
            for (int j = 0; j < i; ++j)
                if (csr[beg + j] == d) { first = false; break; }
            if (first) {
                float e = er + ed[d];
                e = e > 0.f ? e : ALPHA * e;
                ssum += __expf(e - m);
            }
        }
#pragma unroll
        for (int o = 32; o > 0; o >>= 1) ssum += __shfl_xor(ssum, o, 64);
        float acc = 0.f;
        for (int i = 0; i < deg; ++i) {
            int d = csr[beg + i];
            bool first = true;
            for (int j = 0; j < i; ++j)
                if (csr[beg + j] == d) { first = false; break; }
            if (first) {
                float e = er + ed[d];
                e = e > 0.f ? e : ALPHA * e;
                acc = fmaf(__expf(e - m), Wh[(size_t)d * OUT_DIM + lane], acc);
            }
        }
        out[(size_t)r * OUT_DIM + lane] = acc / ssum;
    }
}

// ---------------------------------------------------------------------------
extern "C" void kernel_launch(void* const* d_in, const int* in_sizes, int n_in,
                              void* d_out, int out_size, void* d_ws, size_t ws_size,
                              hipStream_t stream) {
    const float* X     = (const float*)d_in[0];
    const int*   edges = (const int*)d_in[1];
    const float* W     = (const float*)d_in[2];
    const float* a     = (const float*)d_in[3];
    float* out = (float*)d_out;

    const int E = in_sizes[1] / 2;
    const int* src = edges;
    const int* dst = edges + E;

    char* ws = (char*)d_ws;
    size_t o = 0;
    auto carve = [&](size_t bytes) -> void* {
        o = (o + 255) & ~(size_t)255;
        void* p = ws + o;
        o += bytes;
        return p;
    };
    float* Wh  = (float*)carve((size_t)N_NODES * OUT_DIM * 4);
    float* es  = (float*)carve((size_t)N_NODES * 4);
    float* ed  = (float*)carve((size_t)N_NODES * 4);
    int*   cur = (int*)carve((size_t)N_NODES * 4);

    size_t slots_off = (o + 255) & ~(size_t)255;
    size_t need_fast = slots_off + (size_t)N_NODES * CAPS * 8;

    if (ws_size >= need_fast) {
        int2* slots = (int2*)(ws + slots_off);
        k_gemm      <<<1250, 256, 0, stream>>>(X, W, a, Wh, es, ed, cur);
        k_fill_slots<<<(E + 255) / 256, 256, 0, stream>>>(src, dst, E, es, ed, cur, slots);
        k_attn_slots<<<N_NODES, 64, 0, stream>>>(cur, slots, Wh, out);
    } else {
        int* cnt = (int*)carve((size_t)N_NODES * 4);
        int* off = (int*)carve((size_t)(N_NODES + 1) * 4);
        int* csr = (int*)carve((size_t)E * 4);
        k_gemm <<<1250, 256, 0, stream>>>(X, W, a, Wh, es, ed, cnt);
        k_count<<<(E + 255) / 256, 256, 0, stream>>>(src, E, cnt);
        k_scan <<<1, 1024, 0, stream>>>(cnt, off, cur, N_NODES, E);
        k_fill <<<(E + 255) / 256, 256, 0, stream>>>(src, dst, E, cur, csr);
        k_attn <<<N_NODES, 64, 0, stream>>>(off, csr, es, ed, Wh, out);
    }
}

// Round 8
// 64.653 us; speedup vs baseline: 1.2619x; 1.2473x over previous
//
#include <hip/hip_runtime.h>

#define N_NODES 10000
#define IN_DIM  256
#define OUT_DIM 64
#define ALPHA   0.2f
#define CAPS    128   // slot capacity/row (mean deg 32, max ~66; P(>128) ~ 1e-40, clamped)
#define CAP     256   // CSR-fallback LDS edge capacity

typedef __attribute__((ext_vector_type(8))) short short8v;  // 8 bf16 (4 VGPRs)
typedef __attribute__((ext_vector_type(4))) float f32x4;    // 4 fp32 acc

__device__ __forceinline__ ushort f2bf(float f) {
    // RNE fp32 -> bf16
    unsigned u = __float_as_uint(f);
    return (ushort)((u + 0x7FFFu + ((u >> 16) & 1u)) >> 16);
}

// ---------------------------------------------------------------------------
// Kernel 1 (MFMA): Wh = X @ W (10000x256 @ 256x64) in bf16 MFMA + scores.
// Rounds 2/5/6/7 lesson: every fp32-VALU GEMM variant was latency-bound at
// 30-46us (VALUBusy<=13%). MFMA instead: 625 blocks x 4 waves; wave ct owns
// C-tile rows [16b..16b+16) x cols [16ct..16ct+16), K-loop 8 steps.
// A (X) loaded per-lane: row = lane&15, k = 8*(lane>>4)+j  (32B/lane/step).
// B (W) staged ONCE per block into LDS in fragment order with the SAME
// (g,j)->k map, so any consistent HW k-permutation cancels. C/D layout is
// the m89-verified col=lane&15, row=(lane>>4)*4+reg.
// es/ed: per-16-lane-group shfl_xor reduce + LDS atomic, then 16 threads store.
// Also zeroes cur[] for k_fill_slots. Round-3 lesson: no grid.sync() fusion.
// ---------------------------------------------------------------------------
__global__ __launch_bounds__(256) void k_gemm_mfma(const float* __restrict__ X,
                                                   const float* __restrict__ W,
                                                   const float* __restrict__ a,
                                                   float* __restrict__ Wh,
                                                   float* __restrict__ es,
                                                   float* __restrict__ ed,
                                                   int* __restrict__ zero10k) {
    const int t = threadIdx.x;
    const int b = blockIdx.x;
    const int gid = b * 256 + t;
    if (gid < N_NODES) zero10k[gid] = 0;

    __shared__ short8v bfragv[8 * 4 * 64];   // [s][ct][lane] = short8 (32 KB)
    __shared__ float les[16], led[16];

    // stage W -> bf16 B-fragments: elem j of bfragv[(s*4+ct)*64 + g*16+li]
    // holds W[32s + 8g + j][16ct + li]
    for (int w = t; w < IN_DIM * OUT_DIM; w += 256) {
        int k = w >> 6, c = w & 63;
        int s = k >> 5, k5 = k & 31, g = k5 >> 3, j = k5 & 7;
        int ct = c >> 4, li = c & 15;
        ((ushort*)bfragv)[(((s * 4 + ct) * 64) + (g * 16 + li)) * 8 + j] = f2bf(W[w]);
    }
    if (t < 16) { les[t] = 0.f; led[t] = 0.f; }
    __syncthreads();

    const int wave = t >> 6;          // = col-tile ct
    const int lane = t & 63;
    const int g = lane >> 4, li = lane & 15;
    const int row0 = b * 16;          // 625 * 16 = 10000 exactly
    const float* __restrict__ xrow = X + (size_t)(row0 + li) * IN_DIM + g * 8;

    f32x4 acc = {0.f, 0.f, 0.f, 0.f};
#pragma unroll
    for (int s = 0; s < 8; ++s) {
        float4 xa = *(const float4*)(xrow + s * 32);
        float4 xb = *(const float4*)(xrow + s * 32 + 4);
        short8v af;
        af[0] = (short)f2bf(xa.x); af[1] = (short)f2bf(xa.y);
        af[2] = (short)f2bf(xa.z); af[3] = (short)f2bf(xa.w);
        af[4] = (short)f2bf(xb.x); af[5] = (short)f2bf(xb.y);
        af[6] = (short)f2bf(xb.z); af[7] = (short)f2bf(xb.w);
        short8v bfv = bfragv[(s * 4 + wave) * 64 + lane];
        acc = __builtin_amdgcn_mfma_f32_16x16x32_bf16(af, bfv, acc, 0, 0, 0);
    }

    // C/D: col = lane&15 (global 16*wave+li), row = (lane>>4)*4 + j
    const int colC = wave * 16 + li;
    const float asrc = a[colC];
    const float adst = a[OUT_DIM + colC];
#pragma unroll
    for (int j = 0; j < 4; ++j) {
        int row = row0 + g * 4 + j;
        float v = acc[j];
        Wh[(size_t)row * OUT_DIM + colC] = v;
        float se = v * asrc, sd = v * adst;
        // reduce over the 16 lanes of this group (cols of the tile)
        se += __shfl_xor(se, 1, 64); sd += __shfl_xor(sd, 1, 64);
        se += __shfl_xor(se, 2, 64); sd += __shfl_xor(sd, 2, 64);
        se += __shfl_xor(se, 4, 64); sd += __shfl_xor(sd, 4, 64);
        se += __shfl_xor(se, 8, 64); sd += __shfl_xor(sd, 8, 64);
        if (li == 0) {
            atomicAdd(&les[g * 4 + j], se);
            atomicAdd(&led[g * 4 + j], sd);
        }
    }
    __syncthreads();
    if (t < 16) { es[row0 + t] = les[t]; ed[row0 + t] = led[t]; }
}

// ---------------------------------------------------------------------------
// Kernel 2: scatter edges into fixed-stride per-row buckets, storing the
// FINISHED score {dst, e = leakyrelu(es[s]+ed[d])}. es/ed 40KB, cache-resident.
// ---------------------------------------------------------------------------
__global__ void k_fill_slots(const int* __restrict__ src, const int* __restrict__ dst,
                             int E, const float* __restrict__ es,
                             const float* __restrict__ ed,
                             int* __restrict__ cur, int2* __restrict__ slots) {
    int i = blockIdx.x * 256 + threadIdx.x;
    if (i < E) {
        int s = src[i], d = dst[i];
        float e = es[s] + ed[d];
        e = e > 0.f ? e : ALPHA * e;
        int p = atomicAdd(&cur[s], 1);
        if (p < CAPS) slots[(size_t)s * CAPS + p] = make_int2(d, __float_as_int(e));
    }
}

// ---------------------------------------------------------------------------
// Kernel 3: one wave per row. Dedupe duplicate (src,dst) pairs (reference
// .at[].set counts each unique pair ONCE; duplicate e identical), softmax,
// h' = sum p_i/S * Wh[dst_i,:]. lane = out dim -> 256B coalesced Wh gathers.
// ---------------------------------------------------------------------------
__global__ __launch_bounds__(64) void k_attn_slots(const int* __restrict__ cur,
                                                   const int2* __restrict__ slots,
                                                   const float* __restrict__ Wh,
                                                   float* __restrict__ out) {
    const int r = blockIdx.x;
    const int lane = threadIdx.x;
    int deg = cur[r];
    if (deg > CAPS) deg = CAPS;

    if (deg == 0) {
        // softmax of all-NEG_FILL row is uniform -> column mean of Wh
        float acc = 0.f;
        for (int j = 0; j < N_NODES; ++j) acc += Wh[(size_t)j * OUT_DIM + lane];
        out[(size_t)r * OUT_DIM + lane] = acc / (float)N_NODES;
        return;
    }

    __shared__ int   sdst[CAPS];
    __shared__ float sp[CAPS];

    // pass A: load finished slot pairs
    for (int i = lane; i < deg; i += 64) {
        int2 v = slots[(size_t)r * CAPS + i];
        sdst[i] = v.x;
        sp[i]   = __int_as_float(v.y);
    }
    __syncthreads();

    // pass B: dedupe-mark + row max
    float m = -INFINITY;
    for (int i = lane; i < deg; i += 64) {
        int d = sdst[i];
        bool first = true;
        for (int j = 0; j < i; ++j)
            if (sdst[j] == d) { first = false; break; }
        if (first) m = fmaxf(m, sp[i]);
        else       sp[i] = -INFINITY;     // exp() -> 0
    }
#pragma unroll
    for (int o = 32; o > 0; o >>= 1) m = fmaxf(m, __shfl_xor(m, o, 64));
    __syncthreads();

    // pass C: exp + sum
    float ssum = 0.f;
    for (int i = lane; i < deg; i += 64) {
        float p = __expf(sp[i] - m);
        sp[i] = p;
        ssum += p;
    }
#pragma unroll
    for (int o = 32; o > 0; o >>= 1) ssum += __shfl_xor(ssum, o, 64);
    __syncthreads();

    // pass D: accumulate h', 4 gathers in flight
    float acc = 0.f;
    int i = 0;
    for (; i + 4 <= deg; i += 4) {
        float p0 = sp[i + 0], p1 = sp[i + 1], p2 = sp[i + 2], p3 = sp[i + 3];
        int   q0 = sdst[i + 0], q1 = sdst[i + 1], q2 = sdst[i + 2], q3 = sdst[i + 3];
        float w0 = Wh[(size_t)q0 * OUT_DIM + lane];
        float w1 = Wh[(size_t)q1 * OUT_DIM + lane];
        float w2 = Wh[(size_t)q2 * OUT_DIM + lane];
        float w3 = Wh[(size_t)q3 * OUT_DIM + lane];
        acc = fmaf(p0, w0, acc);
        acc = fmaf(p1, w1, acc);
        acc = fmaf(p2, w2, acc);
        acc = fmaf(p3, w3, acc);
    }
    for (; i < deg; ++i)
        acc = fmaf(sp[i], Wh[(size_t)sdst[i] * OUT_DIM + lane], acc);

    out[(size_t)r * OUT_DIM + lane] = acc / ssum;
}

// ---------------------------------------------------------------------------
// CSR FALLBACK (only if ws can't hold the slot buckets).
// ---------------------------------------------------------------------------
__global__ void k_count(const int* __restrict__ src, int E, int* __restrict__ cnt) {
    int i = blockIdx.x * 256 + threadIdx.x;
    if (i < E) atomicAdd(&cnt[src[i]], 1);
}

__global__ __launch_bounds__(1024) void k_scan(const int* __restrict__ cnt,
                                               int* __restrict__ off,
                                               int* __restrict__ cur,
                                               int n, int E) {
    __shared__ int part[1024];
    const int t = threadIdx.x;
    const int CH = (N_NODES + 1023) / 1024;
    int beg = t * CH, end = min(beg + CH, n);
    int s = 0;
    for (int i = beg; i < end; ++i) s += cnt[i];
    part[t] = s;
    __syncthreads();
    for (int d = 1; d < 1024; d <<= 1) {
        int v = (t >= d) ? part[t - d] : 0;
        __syncthreads();
        part[t] += v;
        __syncthreads();
    }
    int run = (t == 0) ? 0 : part[t - 1];
    for (int i = beg; i < end; ++i) {
        off[i] = run;
        cur[i] = run;
        run += cnt[i];
    }
    if (t == 0) off[n] = E;
}

__global__ void k_fill(const int* __restrict__ src, const int* __restrict__ dst, int E,
                       int* __restrict__ cur, int* __restrict__ csr) {
    int i = blockIdx.x * 256 + threadIdx.x;
    if (i < E) {
        int p = atomicAdd(&cur[src[i]], 1);
        csr[p] = dst[i];
    }
}

__global__ __launch_bounds__(64) void k_attn(const int* __restrict__ off,
                                             const int* __restrict__ csr,
                                             const float* __restrict__ es,
                                             const float* __restrict__ ed,
                                             const float* __restrict__ Wh,
                                             float* __restrict__ out) {
    const int r = blockIdx.x;
    const int lane = threadIdx.x;
    const int beg = off[r];
    const int deg = off[r + 1] - beg;
    if (deg == 0) {
        float acc = 0.f;
        for (int j = 0; j < N_NODES; ++j) acc += Wh[(size_t)j * OUT_DIM + lane];
        out[(size_t)r * OUT_DIM + lane] = acc / (float)N_NODES;
        return;
    }
    const float er = es[r];
    __shared__ int   sdst[CAP];
    __shared__ float sp[CAP];
    if (deg <= CAP) {
        for (int i = lane; i < deg; i += 64) sdst[i] = csr[beg + i];
        __syncthreads();
        float m = -INFINITY;
        for (int i = lane; i < deg; i += 64) {
            int d = sdst[i];
            bool first = true;
            for (int j = 0; j < i; ++j)
                if (sdst[j] == d) { first = false; break; }
            float e;
            if (first) {
                e = er + ed[d];
                e = e > 0.f ? e : ALPHA * e;
                m = fmaxf(m, e);
            } else e = -INFINITY;
            sp[i] = e;
        }
#pragma unroll
        for (int o = 32; o > 0; o >>= 1) m = fmaxf(m, __shfl_xor(m, o, 64));
        __syncthreads();
        float ssum = 0.f;
        for (int i = lane; i < deg; i += 64) {
            float p = __expf(sp[i] - m);
            sp[i] = p;
            ssum += p;
        }
#pragma unroll
        for (int o = 32; o > 0; o >>= 1) ssum += __shfl_xor(ssum, o, 64);
        __syncthreads();
        float acc = 0.f;
        for (int i = 0; i < deg; ++i)
            acc = fmaf(sp[i], Wh[(size_t)sdst[i] * OUT_DIM + lane], acc);
        out[(size_t)r * OUT_DIM + lane] = acc / ssum;
    } else {
        float m = -INFINITY;
        for (int i = lane; i < deg; i += 64) {
            int d = csr[beg + i];
            bool first = true;
            for (int j = 0; j < i; ++j)
                if (csr[beg + j] == d) { first = false; break; }
            if (first) {
                float e = er + ed[d];
                e = e > 0.f ? e : ALPHA * e;
                m = fmaxf(m, e);
            }
        }
#pragma unroll
        for (int o = 32; o > 0; o >>= 1) m = fmaxf(m, __shfl_xor(m, o, 64));
        float ssum = 0.f;
        for (int i = lane; i < deg; i += 64) {
            int d = csr[beg + i];
            bool first = true;
            for (int j = 0; j < i; ++j)
                if (csr[beg + j] == d) { first = false; break; }
            if (first) {
                float e = er + ed[d];
                e = e > 0.f ? e : ALPHA * e;
                ssum += __expf(e - m);
            }
        }
#pragma unroll
        for (int o = 32; o > 0; o >>= 1) ssum += __shfl_xor(ssum, o, 64);
        float acc = 0.f;
        for (int i = 0; i < deg; ++i) {
            int d = csr[beg + i];
            bool first = true;
            for (int j = 0; j < i; ++j)
                if (csr[beg + j] == d) { first = false; break; }
            if (first) {
                float e = er + ed[d];
                e = e > 0.f ? e : ALPHA * e;
                acc = fmaf(__expf(e - m), Wh[(size_t)d * OUT_DIM + lane], acc);
            }
        }
        out[(size_t)r * OUT_DIM + lane] = acc / ssum;
    }
}

// ---------------------------------------------------------------------------
extern "C" void kernel_launch(void* const* d_in, const int* in_sizes, int n_in,
                              void* d_out, int out_size, void* d_ws, size_t ws_size,
                              hipStream_t stream) {
    const float* X     = (const float*)d_in[0];
    const int*   edges = (const int*)d_in[1];
    const float* W     = (const float*)d_in[2];
    const float* a     = (const float*)d_in[3];
    float* out = (float*)d_out;

    const int E = in_sizes[1] / 2;
    const int* src = edges;
    const int* dst = edges + E;

    char* ws = (char*)d_ws;
    size_t o = 0;
    auto carve = [&](size_t bytes) -> void* {
        o = (o + 255) & ~(size_t)255;
        void* p = ws + o;
        o += bytes;
        return p;
    };
    float* Wh  = (float*)carve((size_t)N_NODES * OUT_DIM * 4);
    float* es  = (float*)carve((size_t)N_NODES * 4);
    float* ed  = (float*)carve((size_t)N_NODES * 4);
    int*   cur = (int*)carve((size_t)N_NODES * 4);

    size_t slots_off = (o + 255) & ~(size_t)255;
    size_t need_fast = slots_off + (size_t)N_NODES * CAPS * 8;

    if (ws_size >= need_fast) {
        int2* slots = (int2*)(ws + slots_off);
        k_gemm_mfma <<<625, 256, 0, stream>>>(X, W, a, Wh, es, ed, cur);
        k_fill_slots<<<(E + 255) / 256, 256, 0, stream>>>(src, dst, E, es, ed, cur, slots);
        k_attn_slots<<<N_NODES, 64, 0, stream>>>(cur, slots, Wh, out);
    } else {
        int* cnt = (int*)carve((size_t)N_NODES * 4);
        int* off = (int*)carve((size_t)(N_NODES + 1) * 4);
        int* csr = (int*)carve((size_t)E * 4);
        k_gemm_mfma <<<625, 256, 0, stream>>>(X, W, a, Wh, es, ed, cnt);
        k_count<<<(E + 255) / 256, 256, 0, stream>>>(src, E, cnt);
        k_scan <<<1, 1024, 0, stream>>>(cnt, off, cur, N_NODES, E);
        k_fill <<<(E + 255) / 256, 256, 0, stream>>>(src, dst, E, cur, csr);
        k_attn <<<N_NODES, 64, 0, stream>>>(off, csr, es, ed, Wh, out);
    }
}

// Round 9
// 55.439 us; speedup vs baseline: 1.4717x; 1.1662x over previous
//
#include <hip/hip_runtime.h>

#define N_NODES 10000
#define IN_DIM  256
#define OUT_DIM 64
#define ALPHA   0.2f
#define CAPS    128   // slot capacity/row (mean deg 32, max ~66; P(>128) ~ 1e-40, clamped)
#define CAP     256   // CSR-fallback LDS edge capacity

typedef __attribute__((ext_vector_type(8))) short short8v;  // 8 bf16 (4 VGPRs)
typedef __attribute__((ext_vector_type(4))) float f32x4;    // 4 fp32 acc

__device__ __forceinline__ ushort f2bf(float f) {
    unsigned u = __float_as_uint(f);
    return (ushort)((u + 0x7FFFu + ((u >> 16) & 1u)) >> 16);   // RNE
}
__device__ __forceinline__ float bf2f(ushort u) {
    return __uint_as_float((unsigned)u << 16);
}

// ---------------------------------------------------------------------------
// Kernel 1 (MFMA): Wh = X @ W (bf16 MFMA) + scores es/ed. Wh stored BF16
// (Whb) — attn gathers half the bytes. 625 blocks x 4 waves, wave = col-tile.
// A: row=lane&15, k=8*(lane>>4)+j. B staged once to LDS in fragment order
// with the same (g,j)->k map (consistent k-permutation cancels). C/D layout
// m89-verified: col=lane&15, row=(lane>>4)*4+reg.
// Also zeroes cur[]. Round-3 lesson: no grid.sync() fusion (69->240us).
// Rounds 5-7 lesson: fp32-VALU GEMM is latency-bound at 30-46us; MFMA fixed it.
// ---------------------------------------------------------------------------
__global__ __launch_bounds__(256) void k_gemm_mfma(const float* __restrict__ X,
                                                   const float* __restrict__ W,
                                                   const float* __restrict__ a,
                                                   ushort* __restrict__ Whb,
                                                   float* __restrict__ es,
                                                   float* __restrict__ ed,
                                                   int* __restrict__ zero10k) {
    const int t = threadIdx.x;
    const int b = blockIdx.x;
    const int gid = b * 256 + t;
    if (gid < N_NODES) zero10k[gid] = 0;

    __shared__ short8v bfragv[8 * 4 * 64];   // [s][ct][lane] (32 KB)
    __shared__ float les[16], led[16];

    for (int w = t; w < IN_DIM * OUT_DIM; w += 256) {
        int k = w >> 6, c = w & 63;
        int s = k >> 5, k5 = k & 31, g = k5 >> 3, j = k5 & 7;
        int ct = c >> 4, li = c & 15;
        ((ushort*)bfragv)[(((s * 4 + ct) * 64) + (g * 16 + li)) * 8 + j] = f2bf(W[w]);
    }
    if (t < 16) { les[t] = 0.f; led[t] = 0.f; }
    __syncthreads();

    const int wave = t >> 6;          // col-tile ct
    const int lane = t & 63;
    const int g = lane >> 4, li = lane & 15;
    const int row0 = b * 16;          // 625 * 16 = 10000 exactly
    const float* __restrict__ xrow = X + (size_t)(row0 + li) * IN_DIM + g * 8;

    f32x4 acc = {0.f, 0.f, 0.f, 0.f};
#pragma unroll
    for (int s = 0; s < 8; ++s) {
        float4 xa = *(const float4*)(xrow + s * 32);
        float4 xb = *(const float4*)(xrow + s * 32 + 4);
        short8v af;
        af[0] = (short)f2bf(xa.x); af[1] = (short)f2bf(xa.y);
        af[2] = (short)f2bf(xa.z); af[3] = (short)f2bf(xa.w);
        af[4] = (short)f2bf(xb.x); af[5] = (short)f2bf(xb.y);
        af[6] = (short)f2bf(xb.z); af[7] = (short)f2bf(xb.w);
        short8v bfv = bfragv[(s * 4 + wave) * 64 + lane];
        acc = __builtin_amdgcn_mfma_f32_16x16x32_bf16(af, bfv, acc, 0, 0, 0);
    }

    const int colC = wave * 16 + li;
    const float asrc = a[colC];
    const float adst = a[OUT_DIM + colC];
#pragma unroll
    for (int j = 0; j < 4; ++j) {
        int row = row0 + g * 4 + j;
        float v = acc[j];
        Whb[(size_t)row * OUT_DIM + colC] = f2bf(v);
        float se = v * asrc, sd = v * adst;
        se += __shfl_xor(se, 1, 64); sd += __shfl_xor(sd, 1, 64);
        se += __shfl_xor(se, 2, 64); sd += __shfl_xor(sd, 2, 64);
        se += __shfl_xor(se, 4, 64); sd += __shfl_xor(sd, 4, 64);
        se += __shfl_xor(se, 8, 64); sd += __shfl_xor(sd, 8, 64);
        if (li == 0) {
            atomicAdd(&les[g * 4 + j], se);
            atomicAdd(&led[g * 4 + j], sd);
        }
    }
    __syncthreads();
    if (t < 16) { es[row0 + t] = les[t]; ed[row0 + t] = led[t]; }
}

// ---------------------------------------------------------------------------
// Kernel 2: scatter edges into per-row buckets with finished score
// {dst, e = leakyrelu(es[s]+ed[d])}. es/ed 40KB, cache-resident.
// ---------------------------------------------------------------------------
__global__ void k_fill_slots(const int* __restrict__ src, const int* __restrict__ dst,
                             int E, const float* __restrict__ es,
                             const float* __restrict__ ed,
                             int* __restrict__ cur, int2* __restrict__ slots) {
    int i = blockIdx.x * 256 + threadIdx.x;
    if (i < E) {
        int s = src[i], d = dst[i];
        float e = es[s] + ed[d];
        e = e > 0.f ? e : ALPHA * e;
        int p = atomicAdd(&cur[s], 1);
        if (p < CAPS) slots[(size_t)s * CAPS + p] = make_int2(d, __float_as_int(e));
    }
}

// ---------------------------------------------------------------------------
// Kernel 3: one wave per row. Round-9: O(deg) LDS-hash dedupe (256-entry
// atomicCAS open addressing; the surviving duplicate is arbitrary — legal,
// e-values of duplicates are identical), PV unroll x8, bf16 Wh gathers
// (128B/row instead of 256B).
// ---------------------------------------------------------------------------
__global__ __launch_bounds__(64) void k_attn_slots(const int* __restrict__ cur,
                                                   const int2* __restrict__ slots,
                                                   const ushort* __restrict__ Whb,
                                                   float* __restrict__ out) {
    const int r = blockIdx.x;
    const int lane = threadIdx.x;
    int deg = cur[r];
    if (deg > CAPS) deg = CAPS;

    if (deg == 0) {
        // softmax of all-NEG_FILL row is uniform -> column mean of Wh
        float acc = 0.f;
        for (int j = 0; j < N_NODES; ++j) acc += bf2f(Whb[(size_t)j * OUT_DIM + lane]);
        out[(size_t)r * OUT_DIM + lane] = acc / (float)N_NODES;
        return;
    }

    __shared__ int   htab[256];
    __shared__ int   sdst[CAPS];
    __shared__ float sp[CAPS];

    for (int i = lane; i < 256; i += 64) htab[i] = -1;
    __syncthreads();   // 1 wave -> compiles to a waitcnt, cheap

    // pass A: load slots, hash-dedupe, leaky already applied; track max
    float m = -INFINITY;
    for (int i = lane; i < deg; i += 64) {
        int2 v = slots[(size_t)r * CAPS + i];
        int d = v.x;
        float e = __int_as_float(v.y);
        bool first = true;
        unsigned h = ((unsigned)d * 2654435761u) >> 24;
        while (true) {
            int prev = atomicCAS(&htab[h], -1, d);
            if (prev == -1) break;                    // inserted: first
            if (prev == d) { first = false; break; }  // duplicate
            h = (h + 1) & 255;
        }
        if (!first) e = -INFINITY;                    // exp() -> 0
        sdst[i] = d;
        sp[i] = e;
        m = fmaxf(m, e);
    }
#pragma unroll
    for (int o = 32; o > 0; o >>= 1) m = fmaxf(m, __shfl_xor(m, o, 64));
    __syncthreads();

    // pass B: exp + sum
    float ssum = 0.f;
    for (int i = lane; i < deg; i += 64) {
        float p = __expf(sp[i] - m);
        sp[i] = p;
        ssum += p;
    }
#pragma unroll
    for (int o = 32; o > 0; o >>= 1) ssum += __shfl_xor(ssum, o, 64);
    __syncthreads();

    // pass C: accumulate h', 8 bf16 gathers in flight
    float acc = 0.f;
    int i = 0;
    for (; i + 8 <= deg; i += 8) {
        float p[8]; int q[8]; float w[8];
#pragma unroll
        for (int u = 0; u < 8; ++u) { p[u] = sp[i + u]; q[u] = sdst[i + u]; }
#pragma unroll
        for (int u = 0; u < 8; ++u) w[u] = bf2f(Whb[(size_t)q[u] * OUT_DIM + lane]);
#pragma unroll
        for (int u = 0; u < 8; ++u) acc = fmaf(p[u], w[u], acc);
    }
    for (; i < deg; ++i)
        acc = fmaf(sp[i], bf2f(Whb[(size_t)sdst[i] * OUT_DIM + lane]), acc);

    out[(size_t)r * OUT_DIM + lane] = acc / ssum;
}

// ---------------------------------------------------------------------------
// CSR FALLBACK (only if ws can't hold the slot buckets).
// ---------------------------------------------------------------------------
__global__ void k_count(const int* __restrict__ src, int E, int* __restrict__ cnt) {
    int i = blockIdx.x * 256 + threadIdx.x;
    if (i < E) atomicAdd(&cnt[src[i]], 1);
}

__global__ __launch_bounds__(1024) void k_scan(const int* __restrict__ cnt,
                                               int* __restrict__ off,
                                               int* __restrict__ cur,
                                               int n, int E) {
    __shared__ int part[1024];
    const int t = threadIdx.x;
    const int CH = (N_NODES + 1023) / 1024;
    int beg = t * CH, end = min(beg + CH, n);
    int s = 0;
    for (int i = beg; i < end; ++i) s += cnt[i];
    part[t] = s;
    __syncthreads();
    for (int d = 1; d < 1024; d <<= 1) {
        int v = (t >= d) ? part[t - d] : 0;
        __syncthreads();
        part[t] += v;
        __syncthreads();
    }
    int run = (t == 0) ? 0 : part[t - 1];
    for (int i = beg; i < end; ++i) {
        off[i] = run;
        cur[i] = run;
        run += cnt[i];
    }
    if (t == 0) off[n] = E;
}

__global__ void k_fill(const int* __restrict__ src, const int* __restrict__ dst, int E,
                       int* __restrict__ cur, int* __restrict__ csr) {
    int i = blockIdx.x * 256 + threadIdx.x;
    if (i < E) {
        int p = atomicAdd(&cur[src[i]], 1);
        csr[p] = dst[i];
    }
}

__global__ __launch_bounds__(64) void k_attn(const int* __restrict__ off,
                                             const int* __restrict__ csr,
                                             const float* __restrict__ es,
                                             const float* __restrict__ ed,
                                             const ushort* __restrict__ Whb,
                                             float* __restrict__ out) {
    const int r = blockIdx.x;
    const int lane = threadIdx.x;
    const int beg = off[r];
    const int deg = off[r + 1] - beg;
    if (deg == 0) {
        float acc = 0.f;
        for (int j = 0; j < N_NODES; ++j) acc += bf2f(Whb[(size_t)j * OUT_DIM + lane]);
        out[(size_t)r * OUT_DIM + lane] = acc / (float)N_NODES;
        return;
    }
    const float er = es[r];
    __shared__ int   sdst[CAP];
    __shared__ float sp[CAP];
    if (deg <= CAP) {
        for (int i = lane; i < deg; i += 64) sdst[i] = csr[beg + i];
        __syncthreads();
        float m = -INFINITY;
        for (int i = lane; i < deg; i += 64) {
            int d = sdst[i];
            bool first = true;
            for (int j = 0; j < i; ++j)
                if (sdst[j] == d) { first = false; break; }
            float e;
            if (first) {
                e = er + ed[d];
                e = e > 0.f ? e : ALPHA * e;
                m = fmaxf(m, e);
            } else e = -INFINITY;
            sp[i] = e;
        }
#pragma unroll
        for (int o = 32; o > 0; o >>= 1) m = fmaxf(m, __shfl_xor(m, o, 64));
        __syncthreads();
        float ssum = 0.f;
        for (int i = lane; i < deg; i += 64) {
            float p = __expf(sp[i] - m);
            sp[i] = p;
            ssum += p;
        }
#pragma unroll
        for (int o = 32; o > 0; o >>= 1) ssum += __shfl_xor(ssum, o, 64);
        __syncthreads();
        float acc = 0.f;
        for (int i = 0; i < deg; ++i)
            acc = fmaf(sp[i], bf2f(Whb[(size_t)sdst[i] * OUT_DIM + lane]), acc);
        out[(size_t)r * OUT_DIM + lane] = acc / ssum;
    } else {
        float m = -INFINITY;
        for (int i = lane; i < deg; i += 64) {
            int d = csr[beg + i];
            bool first = true;
            for (int j = 0; j < i; ++j)
                if (csr[beg + j] == d) { first = false; break; }
            if (first) {
                float e = er + ed[d];
                e = e > 0.f ? e : ALPHA * e;
                m = fmaxf(m, e);
            }
        }
#pragma unroll
        for (int o = 32; o > 0; o >>= 1) m = fmaxf(m, __shfl_xor(m, o, 64));
        float ssum = 0.f;
        for (int i = lane; i < deg; i += 64) {
            int d = csr[beg + i];
            bool first = true;
            for (int j = 0; j < i; ++j)
                if (csr[beg + j] == d) { first = false; break; }
            if (first) {
                float e = er + ed[d];
                e = e > 0.f ? e : ALPHA * e;
                ssum += __expf(e - m);
            }
        }
#pragma unroll
        for (int o = 32; o > 0; o >>= 1) ssum += __shfl_xor(ssum, o, 64);
        float acc = 0.f;
        for (int i = 0; i < deg; ++i) {
            int d = csr[beg + i];
            bool first = true;
            for (int j = 0; j < i; ++j)
                if (csr[beg + j] == d) { first = false; break; }
            if (first) {
                float e = er + ed[d];
                e = e > 0.f ? e : ALPHA * e;
                acc = fmaf(__expf(e - m), bf2f(Whb[(size_t)d * OUT_DIM + lane]), acc);
            }
        }
        out[(size_t)r * OUT_DIM + lane] = acc / ssum;
    }
}

// ---------------------------------------------------------------------------
extern "C" void kernel_launch(void* const* d_in, const int* in_sizes, int n_in,
                              void* d_out, int out_size, void* d_ws, size_t ws_size,
                              hipStream_t stream) {
    const float* X     = (const float*)d_in[0];
    const int*   edges = (const int*)d_in[1];
    const float* W     = (const float*)d_in[2];
    const float* a     = (const float*)d_in[3];
    float* out = (float*)d_out;

    const int E = in_sizes[1] / 2;
    const int* src = edges;
    const int* dst = edges + E;

    char* ws = (char*)d_ws;
    size_t o = 0;
    auto carve = [&](size_t bytes) -> void* {
        o = (o + 255) & ~(size_t)255;
        void* p = ws + o;
        o += bytes;
        return p;
    };
    ushort* Whb = (ushort*)carve((size_t)N_NODES * OUT_DIM * 2);
    float*  es  = (float*)carve((size_t)N_NODES * 4);
    float*  ed  = (float*)carve((size_t)N_NODES * 4);
    int*    cur = (int*)carve((size_t)N_NODES * 4);

    size_t slots_off = (o + 255) & ~(size_t)255;
    size_t need_fast = slots_off + (size_t)N_NODES * CAPS * 8;

    if (ws_size >= need_fast) {
        int2* slots = (int2*)(ws + slots_off);
        k_gemm_mfma <<<625, 256, 0, stream>>>(X, W, a, Whb, es, ed, cur);
        k_fill_slots<<<(E + 255) / 256, 256, 0, stream>>>(src, dst, E, es, ed, cur, slots);
        k_attn_slots<<<N_NODES, 64, 0, stream>>>(cur, slots, Whb, out);
    } else {
        int* cnt = (int*)carve((size_t)N_NODES * 4);
        int* off = (int*)carve((size_t)(N_NODES + 1) * 4);
        int* csr = (int*)carve((size_t)E * 4);
        k_gemm_mfma <<<625, 256, 0, stream>>>(X, W, a, Whb, es, ed, cnt);
        k_count<<<(E + 255) / 256, 256, 0, stream>>>(src, E, cnt);
        k_scan <<<1, 1024, 0, stream>>>(cnt, off, cur, N_NODES, E);
        k_fill <<<(E + 255) / 256, 256, 0, stream>>>(src, dst, E, cur, csr);
        k_attn <<<N_NODES, 64, 0, stream>>>(off, csr, es, ed, Whb, out);
    }
}

// Round 10
// 49.223 us; speedup vs baseline: 1.6575x; 1.1263x over previous
//
#include <hip/hip_runtime.h>

#define N_NODES 10000
#define IN_DIM  256
#define OUT_DIM 64
#define ALPHA   0.2f
#define CAPS    128   // slot capacity/row (mean deg 32, max ~66; P(>128) ~ 1e-40, clamped)
#define NBG     625   // gemm blocks (625 x 16 rows = 10000)

typedef __attribute__((ext_vector_type(8))) short short8v;  // 8 bf16 (4 VGPRs)
typedef __attribute__((ext_vector_type(4))) float f32x4;    // 4 fp32 acc

__device__ __forceinline__ ushort f2bf(float f) {
    unsigned u = __float_as_uint(f);
    return (ushort)((u + 0x7FFFu + ((u >> 16) & 1u)) >> 16);   // RNE
}
__device__ __forceinline__ float bf2f(ushort u) {
    return __uint_as_float((unsigned)u << 16);
}

// ---------------------------------------------------------------------------
// Dispatch 1 (fused, heterogeneous blocks):
//   blocks [0, 625): bf16-MFMA GEMM Wh=X@W (stored bf16) + scores es/ed.
//   blocks [625, ..): edge scatter into per-row buckets storing ONLY dst (4B)
//     — independent of the GEMM (score computed later in attn from es/ed),
//     so it runs CONCURRENTLY with the gemm blocks, hiding its cost.
// cur[] is zeroed by a 40KB memsetAsync before this dispatch.
// Round-3 lesson: no grid.sync() fusion (69->240us). Rounds 5-7 lesson:
// fp32-VALU GEMM is latency-bound (30-46us); MFMA fixed it (R8).
// MFMA layout: A row=lane&15, k=8*(lane>>4)+j; B staged to LDS in fragment
// order with the same (g,j)->k map (consistent k-permutation cancels);
// C/D m89-verified: col=lane&15, row=(lane>>4)*4+reg.
// ---------------------------------------------------------------------------
__global__ __launch_bounds__(256) void k_fused(const float* __restrict__ X,
                                               const float* __restrict__ W,
                                               const float* __restrict__ a,
                                               const int* __restrict__ src,
                                               const int* __restrict__ dst,
                                               int E,
                                               ushort* __restrict__ Whb,
                                               float* __restrict__ es,
                                               float* __restrict__ ed,
                                               int* __restrict__ cur,
                                               int* __restrict__ slots) {
    const int t = threadIdx.x;
    const int b = blockIdx.x;

    if (b >= NBG) {
        // ---- scatter role: one thread per edge ----
        int i = (b - NBG) * 256 + t;
        if (i < E) {
            int s = src[i], d = dst[i];
            int p = atomicAdd(&cur[s], 1);
            if (p < CAPS) slots[(size_t)s * CAPS + p] = d;
        }
        return;
    }

    // ---- gemm role ----
    __shared__ short8v bfragv[8 * 4 * 64];   // [s][ct][lane] (32 KB)
    __shared__ float les[16], led[16];

    for (int w = t; w < IN_DIM * OUT_DIM; w += 256) {
        int k = w >> 6, c = w & 63;
        int s = k >> 5, k5 = k & 31, g = k5 >> 3, j = k5 & 7;
        int ct = c >> 4, li = c & 15;
        ((ushort*)bfragv)[(((s * 4 + ct) * 64) + (g * 16 + li)) * 8 + j] = f2bf(W[w]);
    }
    if (t < 16) { les[t] = 0.f; led[t] = 0.f; }
    __syncthreads();

    const int wave = t >> 6;          // col-tile ct
    const int lane = t & 63;
    const int g = lane >> 4, li = lane & 15;
    const int row0 = b * 16;          // 625 * 16 = 10000 exactly
    const float* __restrict__ xrow = X + (size_t)(row0 + li) * IN_DIM + g * 8;

    f32x4 acc = {0.f, 0.f, 0.f, 0.f};
#pragma unroll
    for (int s = 0; s < 8; ++s) {
        float4 xa = *(const float4*)(xrow + s * 32);
        float4 xb = *(const float4*)(xrow + s * 32 + 4);
        short8v af;
        af[0] = (short)f2bf(xa.x); af[1] = (short)f2bf(xa.y);
        af[2] = (short)f2bf(xa.z); af[3] = (short)f2bf(xa.w);
        af[4] = (short)f2bf(xb.x); af[5] = (short)f2bf(xb.y);
        af[6] = (short)f2bf(xb.z); af[7] = (short)f2bf(xb.w);
        short8v bfv = bfragv[(s * 4 + wave) * 64 + lane];
        acc = __builtin_amdgcn_mfma_f32_16x16x32_bf16(af, bfv, acc, 0, 0, 0);
    }

    const int colC = wave * 16 + li;
    const float asrc = a[colC];
    const float adst = a[OUT_DIM + colC];
#pragma unroll
    for (int j = 0; j < 4; ++j) {
        int row = row0 + g * 4 + j;
        float v = acc[j];
        Whb[(size_t)row * OUT_DIM + colC] = f2bf(v);
        float se = v * asrc, sd = v * adst;
        se += __shfl_xor(se, 1, 64); sd += __shfl_xor(sd, 1, 64);
        se += __shfl_xor(se, 2, 64); sd += __shfl_xor(sd, 2, 64);
        se += __shfl_xor(se, 4, 64); sd += __shfl_xor(sd, 4, 64);
        se += __shfl_xor(se, 8, 64); sd += __shfl_xor(sd, 8, 64);
        if (li == 0) {
            atomicAdd(&les[g * 4 + j], se);
            atomicAdd(&led[g * 4 + j], sd);
        }
    }
    __syncthreads();
    if (t < 16) { es[row0 + t] = les[t]; ed[row0 + t] = led[t]; }
}

// ---------------------------------------------------------------------------
// Dispatch 2: one wave per row. Pass A now computes e = leakyrelu(es[r]+ed[d])
// (ed is a 40KB cache-resident table; gather hides in the existing latency
// slack) and slots are 4B. O(deg) LDS-hash dedupe (atomicCAS; surviving
// duplicate arbitrary — legal since duplicate e identical). PV: 8 bf16
// gathers in flight.
// ---------------------------------------------------------------------------
__global__ __launch_bounds__(64) void k_attn_slots(const int* __restrict__ cur,
                                                   const int* __restrict__ slots,
                                                   const float* __restrict__ es,
                                                   const float* __restrict__ ed,
                                                   const ushort* __restrict__ Whb,
                                                   float* __restrict__ out) {
    const int r = blockIdx.x;
    const int lane = threadIdx.x;
    int deg = cur[r];
    if (deg > CAPS) deg = CAPS;

    if (deg == 0) {
        // softmax of all-NEG_FILL row is uniform -> column mean of Wh
        float acc = 0.f;
        for (int j = 0; j < N_NODES; ++j) acc += bf2f(Whb[(size_t)j * OUT_DIM + lane]);
        out[(size_t)r * OUT_DIM + lane] = acc / (float)N_NODES;
        return;
    }

    __shared__ int   htab[256];
    __shared__ int   sdst[CAPS];
    __shared__ float sp[CAPS];

    for (int i = lane; i < 256; i += 64) htab[i] = -1;
    __syncthreads();

    const float er = es[r];

    // pass A: load dst, gather ed, leaky, hash-dedupe, track max
    float m = -INFINITY;
    for (int i = lane; i < deg; i += 64) {
        int d = slots[(size_t)r * CAPS + i];
        float e = er + ed[d];
        e = e > 0.f ? e : ALPHA * e;
        bool first = true;
        unsigned h = ((unsigned)d * 2654435761u) >> 24;
        while (true) {
            int prev = atomicCAS(&htab[h], -1, d);
            if (prev == -1) break;                    // inserted: first
            if (prev == d) { first = false; break; }  // duplicate
            h = (h + 1) & 255;
        }
        if (!first) e = -INFINITY;                    // exp() -> 0
        sdst[i] = d;
        sp[i] = e;
        m = fmaxf(m, e);
    }
#pragma unroll
    for (int o = 32; o > 0; o >>= 1) m = fmaxf(m, __shfl_xor(m, o, 64));
    __syncthreads();

    // pass B: exp + sum
    float ssum = 0.f;
    for (int i = lane; i < deg; i += 64) {
        float p = __expf(sp[i] - m);
        sp[i] = p;
        ssum += p;
    }
#pragma unroll
    for (int o = 32; o > 0; o >>= 1) ssum += __shfl_xor(ssum, o, 64);
    __syncthreads();

    // pass C: accumulate h', 8 bf16 gathers in flight
    float acc = 0.f;
    int i = 0;
    for (; i + 8 <= deg; i += 8) {
        float p[8]; int q[8]; float w[8];
#pragma unroll
        for (int u = 0; u < 8; ++u) { p[u] = sp[i + u]; q[u] = sdst[i + u]; }
#pragma unroll
        for (int u = 0; u < 8; ++u) w[u] = bf2f(Whb[(size_t)q[u] * OUT_DIM + lane]);
#pragma unroll
        for (int u = 0; u < 8; ++u) acc = fmaf(p[u], w[u], acc);
    }
    for (; i < deg; ++i)
        acc = fmaf(sp[i], bf2f(Whb[(size_t)sdst[i] * OUT_DIM + lane]), acc);

    out[(size_t)r * OUT_DIM + lane] = acc / ssum;
}

// ---------------------------------------------------------------------------
// FALLBACK (ws too small for slots): R9-proven separate-kernel path.
// ---------------------------------------------------------------------------
__global__ __launch_bounds__(256) void k_gemm_mfma(const float* __restrict__ X,
                                                   const float* __restrict__ W,
                                                   const float* __restrict__ a,
                                                   ushort* __restrict__ Whb,
                                                   float* __restrict__ es,
                                                   float* __restrict__ ed,
                                                   int* __restrict__ zero10k) {
    const int t = threadIdx.x;
    const int b = blockIdx.x;
    const int gid = b * 256 + t;
    if (gid < N_NODES) zero10k[gid] = 0;

    __shared__ short8v bfragv[8 * 4 * 64];
    __shared__ float les[16], led[16];
    for (int w = t; w < IN_DIM * OUT_DIM; w += 256) {
        int k = w >> 6, c = w & 63;
        int s = k >> 5, k5 = k & 31, g = k5 >> 3, j = k5 & 7;
        int ct = c >> 4, li = c & 15;
        ((ushort*)bfragv)[(((s * 4 + ct) * 64) + (g * 16 + li)) * 8 + j] = f2bf(W[w]);
    }
    if (t < 16) { les[t] = 0.f; led[t] = 0.f; }
    __syncthreads();

    const int wave = t >> 6, lane = t & 63;
    const int g = lane >> 4, li = lane & 15;
    const int row0 = b * 16;
    const float* __restrict__ xrow = X + (size_t)(row0 + li) * IN_DIM + g * 8;

    f32x4 acc = {0.f, 0.f, 0.f, 0.f};
#pragma unroll
    for (int s = 0; s < 8; ++s) {
        float4 xa = *(const float4*)(xrow + s * 32);
        float4 xb = *(const float4*)(xrow + s * 32 + 4);
        short8v af;
        af[0] = (short)f2bf(xa.x); af[1] = (short)f2bf(xa.y);
        af[2] = (short)f2bf(xa.z); af[3] = (short)f2bf(xa.w);
        af[4] = (short)f2bf(xb.x); af[5] = (short)f2bf(xb.y);
        af[6] = (short)f2bf(xb.z); af[7] = (short)f2bf(xb.w);
        short8v bfv = bfragv[(s * 4 + wave) * 64 + lane];
        acc = __builtin_amdgcn_mfma_f32_16x16x32_bf16(af, bfv, acc, 0, 0, 0);
    }
    const int colC = wave * 16 + li;
    const float asrc = a[colC];
    const float adst = a[OUT_DIM + colC];
#pragma unroll
    for (int j = 0; j < 4; ++j) {
        int row = row0 + g * 4 + j;
        float v = acc[j];
        Whb[(size_t)row * OUT_DIM + colC] = f2bf(v);
        float se = v * asrc, sd = v * adst;
        se += __shfl_xor(se, 1, 64); sd += __shfl_xor(sd, 1, 64);
        se += __shfl_xor(se, 2, 64); sd += __shfl_xor(sd, 2, 64);
        se += __shfl_xor(se, 4, 64); sd += __shfl_xor(sd, 4, 64);
        se += __shfl_xor(se, 8, 64); sd += __shfl_xor(sd, 8, 64);
        if (li == 0) { atomicAdd(&les[g * 4 + j], se); atomicAdd(&led[g * 4 + j], sd); }
    }
    __syncthreads();
    if (t < 16) { es[row0 + t] = les[t]; ed[row0 + t] = led[t]; }
}

__global__ void k_fill_slots(const int* __restrict__ src, const int* __restrict__ dst,
                             int E, int* __restrict__ cur, int* __restrict__ slots) {
    int i = blockIdx.x * 256 + threadIdx.x;
    if (i < E) {
        int s = src[i], d = dst[i];
        int p = atomicAdd(&cur[s], 1);
        if (p < CAPS) slots[(size_t)s * CAPS + p] = d;
    }
}

// ---------------------------------------------------------------------------
extern "C" void kernel_launch(void* const* d_in, const int* in_sizes, int n_in,
                              void* d_out, int out_size, void* d_ws, size_t ws_size,
                              hipStream_t stream) {
    const float* X     = (const float*)d_in[0];
    const int*   edges = (const int*)d_in[1];
    const float* W     = (const float*)d_in[2];
    const float* a     = (const float*)d_in[3];
    float* out = (float*)d_out;

    const int E = in_sizes[1] / 2;
    const int* src = edges;
    const int* dst = edges + E;

    char* ws = (char*)d_ws;
    size_t o = 0;
    auto carve = [&](size_t bytes) -> void* {
        o = (o + 255) & ~(size_t)255;
        void* p = ws + o;
        o += bytes;
        return p;
    };
    ushort* Whb   = (ushort*)carve((size_t)N_NODES * OUT_DIM * 2);
    float*  es    = (float*)carve((size_t)N_NODES * 4);
    float*  ed    = (float*)carve((size_t)N_NODES * 4);
    int*    cur   = (int*)carve((size_t)N_NODES * 4);
    int*    slots = (int*)carve((size_t)N_NODES * CAPS * 4);

    const int nsc = (E + 255) / 256;   // scatter blocks

    if (o <= ws_size) {
        hipMemsetAsync(cur, 0, (size_t)N_NODES * 4, stream);        // 40 KB, tiny
        k_fused     <<<NBG + nsc, 256, 0, stream>>>(X, W, a, src, dst, E,
                                                    Whb, es, ed, cur, slots);
        k_attn_slots<<<N_NODES, 64, 0, stream>>>(cur, slots, es, ed, Whb, out);
    } else {
        // fallback: R9-style separate kernels (gemm zeroes cur)
        k_gemm_mfma <<<NBG, 256, 0, stream>>>(X, W, a, Whb, es, ed, cur);
        k_fill_slots<<<nsc, 256, 0, stream>>>(src, dst, E, cur, slots);
        k_attn_slots<<<N_NODES, 64, 0, stream>>>(cur, slots, es, ed, Whb, out);
    }
}

// Round 11
// 46.356 us; speedup vs baseline: 1.7601x; 1.0619x over previous
//
#include <hip/hip_runtime.h>

#define N_NODES 10000
#define IN_DIM  256
#define OUT_DIM 64
#define ALPHA   0.2f
#define CAPS    128   // slot capacity/row (mean deg 32, max ~66; P(>128) ~ 1e-40, clamped)
#define NBG     625   // gemm blocks (625 x 16 rows = 10000)

typedef __attribute__((ext_vector_type(8))) short short8v;  // 8 bf16 (4 VGPRs)
typedef __attribute__((ext_vector_type(4))) float f32x4;    // 4 fp32 acc

__device__ __forceinline__ ushort f2bf(float f) {
    unsigned u = __float_as_uint(f);
    return (ushort)((u + 0x7FFFu + ((u >> 16) & 1u)) >> 16);   // RNE
}
__device__ __forceinline__ float bf2f(ushort u) {
    return __uint_as_float((unsigned)u << 16);
}

// ---------------------------------------------------------------------------
// Dispatch 0 (k_prep): zero cur[] AND build the bf16 W-fragment table Wf in
// global memory (32 KB, L2-resident). Replaces hipMemsetAsync — R10 profile
// showed runtime fill dispatches cost ~40us FIXED regardless of size (tiny
// 20KB fills = 40us, same as 268MB poison fills). Also de-duplicates the W
// staging that every gemm block previously redid (625x).
// Fragment order: elem j of Wf[((s*4+ct)*64 + g*16+li)] = W[32s+8g+j][16ct+li]
// -> same (g,j)->k map as the A-fragment, so any consistent HW k-permutation
// cancels in D = sum_k A[r,k]B[k,c].
// ---------------------------------------------------------------------------
__global__ __launch_bounds__(256) void k_prep(const float* __restrict__ W,
                                              int* __restrict__ cur,
                                              ushort* __restrict__ Wf) {
    const int gid = blockIdx.x * 256 + threadIdx.x;   // 40 blocks -> 10240 threads
    for (int i = gid; i < N_NODES; i += 10240) cur[i] = 0;
    for (int w = gid; w < IN_DIM * OUT_DIM; w += 10240) {
        int k = w >> 6, c = w & 63;
        int s = k >> 5, k5 = k & 31, g = k5 >> 3, j = k5 & 7;
        int ct = c >> 4, li = c & 15;
        Wf[(((s * 4 + ct) * 64) + (g * 16 + li)) * 8 + j] = f2bf(W[w]);
    }
}

// ---------------------------------------------------------------------------
// Dispatch 1 (fused, heterogeneous blocks):
//   blocks [0, 625): bf16-MFMA GEMM Wh=X@W (stored bf16) + scores es/ed.
//     B-fragments loaded straight from global Wf (coalesced 16B/lane, L2-hot).
//   blocks [625, ..): edge scatter into per-row buckets storing ONLY dst (4B)
//     — independent of the GEMM, runs concurrently, cost hidden.
// Round-3 lesson: no grid.sync() fusion (69->240us). Rounds 5-7: fp32-VALU
// GEMM latency-bound (30-46us); MFMA fixed (R8). C/D layout m89-verified:
// col=lane&15, row=(lane>>4)*4+reg.
// ---------------------------------------------------------------------------
__global__ __launch_bounds__(256) void k_fused(const float* __restrict__ X,
                                               const ushort* __restrict__ Wf,
                                               const float* __restrict__ a,
                                               const int* __restrict__ src,
                                               const int* __restrict__ dst,
                                               int E,
                                               ushort* __restrict__ Whb,
                                               float* __restrict__ es,
                                               float* __restrict__ ed,
                                               int* __restrict__ cur,
                                               int* __restrict__ slots) {
    const int t = threadIdx.x;
    const int b = blockIdx.x;

    if (b >= NBG) {
        // ---- scatter role: one thread per edge ----
        int i = (b - NBG) * 256 + t;
        if (i < E) {
            int s = src[i], d = dst[i];
            int p = atomicAdd(&cur[s], 1);
            if (p < CAPS) slots[(size_t)s * CAPS + p] = d;
        }
        return;
    }

    // ---- gemm role ----
    __shared__ float les[16], led[16];
    if (t < 16) { les[t] = 0.f; led[t] = 0.f; }
    __syncthreads();

    const int wave = t >> 6;          // col-tile ct
    const int lane = t & 63;
    const int g = lane >> 4, li = lane & 15;
    const int row0 = b * 16;          // 625 * 16 = 10000 exactly
    const float* __restrict__ xrow = X + (size_t)(row0 + li) * IN_DIM + g * 8;
    const short8v* __restrict__ Wfrag = (const short8v*)Wf;

    f32x4 acc = {0.f, 0.f, 0.f, 0.f};
#pragma unroll
    for (int s = 0; s < 8; ++s) {
        float4 xa = *(const float4*)(xrow + s * 32);
        float4 xb = *(const float4*)(xrow + s * 32 + 4);
        short8v af;
        af[0] = (short)f2bf(xa.x); af[1] = (short)f2bf(xa.y);
        af[2] = (short)f2bf(xa.z); af[3] = (short)f2bf(xa.w);
        af[4] = (short)f2bf(xb.x); af[5] = (short)f2bf(xb.y);
        af[6] = (short)f2bf(xb.z); af[7] = (short)f2bf(xb.w);
        short8v bfv = Wfrag[(s * 4 + wave) * 64 + lane];   // 16B coalesced, L2
        acc = __builtin_amdgcn_mfma_f32_16x16x32_bf16(af, bfv, acc, 0, 0, 0);
    }

    const int colC = wave * 16 + li;
    const float asrc = a[colC];
    const float adst = a[OUT_DIM + colC];
#pragma unroll
    for (int j = 0; j < 4; ++j) {
        int row = row0 + g * 4 + j;
        float v = acc[j];
        Whb[(size_t)row * OUT_DIM + colC] = f2bf(v);
        float se = v * asrc, sd = v * adst;
        se += __shfl_xor(se, 1, 64); sd += __shfl_xor(sd, 1, 64);
        se += __shfl_xor(se, 2, 64); sd += __shfl_xor(sd, 2, 64);
        se += __shfl_xor(se, 4, 64); sd += __shfl_xor(sd, 4, 64);
        se += __shfl_xor(se, 8, 64); sd += __shfl_xor(sd, 8, 64);
        if (li == 0) {
            atomicAdd(&les[g * 4 + j], se);
            atomicAdd(&led[g * 4 + j], sd);
        }
    }
    __syncthreads();
    if (t < 16) { es[row0 + t] = les[t]; ed[row0 + t] = led[t]; }
}

// ---------------------------------------------------------------------------
// Dispatch 2: one wave per row. e = leakyrelu(es[r]+ed[d]) computed here
// (ed 40KB cache-resident). O(deg) LDS-hash dedupe (atomicCAS; surviving
// duplicate arbitrary — duplicates have identical e). PV: 8 bf16 gathers
// in flight.
// ---------------------------------------------------------------------------
__global__ __launch_bounds__(64) void k_attn_slots(const int* __restrict__ cur,
                                                   const int* __restrict__ slots,
                                                   const float* __restrict__ es,
                                                   const float* __restrict__ ed,
                                                   const ushort* __restrict__ Whb,
                                                   float* __restrict__ out) {
    const int r = blockIdx.x;
    const int lane = threadIdx.x;
    int deg = cur[r];
    if (deg > CAPS) deg = CAPS;

    if (deg == 0) {
        // softmax of all-NEG_FILL row is uniform -> column mean of Wh
        float acc = 0.f;
        for (int j = 0; j < N_NODES; ++j) acc += bf2f(Whb[(size_t)j * OUT_DIM + lane]);
        out[(size_t)r * OUT_DIM + lane] = acc / (float)N_NODES;
        return;
    }

    __shared__ int   htab[256];
    __shared__ int   sdst[CAPS];
    __shared__ float sp[CAPS];

    for (int i = lane; i < 256; i += 64) htab[i] = -1;
    __syncthreads();

    const float er = es[r];

    // pass A: load dst, gather ed, leaky, hash-dedupe, track max
    float m = -INFINITY;
    for (int i = lane; i < deg; i += 64) {
        int d = slots[(size_t)r * CAPS + i];
        float e = er + ed[d];
        e = e > 0.f ? e : ALPHA * e;
        bool first = true;
        unsigned h = ((unsigned)d * 2654435761u) >> 24;
        while (true) {
            int prev = atomicCAS(&htab[h], -1, d);
            if (prev == -1) break;                    // inserted: first
            if (prev == d) { first = false; break; }  // duplicate
            h = (h + 1) & 255;
        }
        if (!first) e = -INFINITY;                    // exp() -> 0
        sdst[i] = d;
        sp[i] = e;
        m = fmaxf(m, e);
    }
#pragma unroll
    for (int o = 32; o > 0; o >>= 1) m = fmaxf(m, __shfl_xor(m, o, 64));
    __syncthreads();

    // pass B: exp + sum
    float ssum = 0.f;
    for (int i = lane; i < deg; i += 64) {
        float p = __expf(sp[i] - m);
        sp[i] = p;
        ssum += p;
    }
#pragma unroll
    for (int o = 32; o > 0; o >>= 1) ssum += __shfl_xor(ssum, o, 64);
    __syncthreads();

    // pass C: accumulate h', 8 bf16 gathers in flight
    float acc = 0.f;
    int i = 0;
    for (; i + 8 <= deg; i += 8) {
        float p[8]; int q[8]; float w[8];
#pragma unroll
        for (int u = 0; u < 8; ++u) { p[u] = sp[i + u]; q[u] = sdst[i + u]; }
#pragma unroll
        for (int u = 0; u < 8; ++u) w[u] = bf2f(Whb[(size_t)q[u] * OUT_DIM + lane]);
#pragma unroll
        for (int u = 0; u < 8; ++u) acc = fmaf(p[u], w[u], acc);
    }
    for (; i < deg; ++i)
        acc = fmaf(sp[i], bf2f(Whb[(size_t)sdst[i] * OUT_DIM + lane]), acc);

    out[(size_t)r * OUT_DIM + lane] = acc / ssum;
}

// ---------------------------------------------------------------------------
// FALLBACK (ws too small for slots+Wf): R9-proven separate-kernel path with
// in-kernel W staging.
// ---------------------------------------------------------------------------
__global__ __launch_bounds__(256) void k_gemm_mfma(const float* __restrict__ X,
                                                   const float* __restrict__ W,
                                                   const float* __restrict__ a,
                                                   ushort* __restrict__ Whb,
                                                   float* __restrict__ es,
                                                   float* __restrict__ ed,
                                                   int* __restrict__ zero10k) {
    const int t = threadIdx.x;
    const int b = blockIdx.x;
    const int gid = b * 256 + t;
    if (gid < N_NODES) zero10k[gid] = 0;

    __shared__ short8v bfragv[8 * 4 * 64];
    __shared__ float les[16], led[16];
    for (int w = t; w < IN_DIM * OUT_DIM; w += 256) {
        int k = w >> 6, c = w & 63;
        int s = k >> 5, k5 = k & 31, g = k5 >> 3, j = k5 & 7;
        int ct = c >> 4, li = c & 15;
        ((ushort*)bfragv)[(((s * 4 + ct) * 64) + (g * 16 + li)) * 8 + j] = f2bf(W[w]);
    }
    if (t < 16) { les[t] = 0.f; led[t] = 0.f; }
    __syncthreads();

    const int wave = t >> 6, lane = t & 63;
    const int g = lane >> 4, li = lane & 15;
    const int row0 = b * 16;
    const float* __restrict__ xrow = X + (size_t)(row0 + li) * IN_DIM + g * 8;

    f32x4 acc = {0.f, 0.f, 0.f, 0.f};
#pragma unroll
    for (int s = 0; s < 8; ++s) {
        float4 xa = *(const float4*)(xrow + s * 32);
        float4 xb = *(const float4*)(xrow + s * 32 + 4);
        short8v af;
        af[0] = (short)f2bf(xa.x); af[1] = (short)f2bf(xa.y);
        af[2] = (short)f2bf(xa.z); af[3] = (short)f2bf(xa.w);
        af[4] = (short)f2bf(xb.x); af[5] = (short)f2bf(xb.y);
        af[6] = (short)f2bf(xb.z); af[7] = (short)f2bf(xb.w);
        short8v bfv = bfragv[(s * 4 + wave) * 64 + lane];
        acc = __builtin_amdgcn_mfma_f32_16x16x32_bf16(af, bfv, acc, 0, 0, 0);
    }
    const int colC = wave * 16 + li;
    const float asrc = a[colC];
    const float adst = a[OUT_DIM + colC];
#pragma unroll
    for (int j = 0; j < 4; ++j) {
        int row = row0 + g * 4 + j;
        float v = acc[j];
        Whb[(size_t)row * OUT_DIM + colC] = f2bf(v);
        float se = v * asrc, sd = v * adst;
        se += __shfl_xor(se, 1, 64); sd += __shfl_xor(sd, 1, 64);
        se += __shfl_xor(se, 2, 64); sd += __shfl_xor(sd, 2, 64);
        se += __shfl_xor(se, 4, 64); sd += __shfl_xor(sd, 4, 64);
        se += __shfl_xor(se, 8, 64); sd += __shfl_xor(sd, 8, 64);
        if (li == 0) { atomicAdd(&les[g * 4 + j], se); atomicAdd(&led[g * 4 + j], sd); }
    }
    __syncthreads();
    if (t < 16) { es[row0 + t] = les[t]; ed[row0 + t] = led[t]; }
}

__global__ void k_fill_slots(const int* __restrict__ src, const int* __restrict__ dst,
                             int E, int* __restrict__ cur, int* __restrict__ slots) {
    int i = blockIdx.x * 256 + threadIdx.x;
    if (i < E) {
        int s = src[i], d = dst[i];
        int p = atomicAdd(&cur[s], 1);
        if (p < CAPS) slots[(size_t)s * CAPS + p] = d;
    }
}

// ---------------------------------------------------------------------------
extern "C" void kernel_launch(void* const* d_in, const int* in_sizes, int n_in,
                              void* d_out, int out_size, void* d_ws, size_t ws_size,
                              hipStream_t stream) {
    const float* X     = (const float*)d_in[0];
    const int*   edges = (const int*)d_in[1];
    const float* W     = (const float*)d_in[2];
    const float* a     = (const float*)d_in[3];
    float* out = (float*)d_out;

    const int E = in_sizes[1] / 2;
    const int* src = edges;
    const int* dst = edges + E;

    char* ws = (char*)d_ws;
    size_t o = 0;
    auto carve = [&](size_t bytes) -> void* {
        o = (o + 255) & ~(size_t)255;
        void* p = ws + o;
        o += bytes;
        return p;
    };
    ushort* Whb   = (ushort*)carve((size_t)N_NODES * OUT_DIM * 2);
    float*  es    = (float*)carve((size_t)N_NODES * 4);
    float*  ed    = (float*)carve((size_t)N_NODES * 4);
    int*    cur   = (int*)carve((size_t)N_NODES * 4);
    int*    slots = (int*)carve((size_t)N_NODES * CAPS * 4);
    ushort* Wf    = (ushort*)carve((size_t)IN_DIM * OUT_DIM * 2);

    const int nsc = (E + 255) / 256;   // scatter blocks

    if (o <= ws_size) {
        k_prep      <<<40, 256, 0, stream>>>(W, cur, Wf);
        k_fused     <<<NBG + nsc, 256, 0, stream>>>(X, Wf, a, src, dst, E,
                                                    Whb, es, ed, cur, slots);
        k_attn_slots<<<N_NODES, 64, 0, stream>>>(cur, slots, es, ed, Whb, out);
    } else {
        // fallback: R9-style separate kernels (gemm zeroes cur)
        k_gemm_mfma <<<NBG, 256, 0, stream>>>(X, W, a, Whb, es, ed, cur);
        k_fill_slots<<<nsc, 256, 0, stream>>>(src, dst, E, cur, slots);
        k_attn_slots<<<N_NODES, 64, 0, stream>>>(cur, slots, es, ed, Whb, out);
    }
}

// Round 12
// 44.782 us; speedup vs baseline: 1.8219x; 1.0351x over previous
//
#include <hip/hip_runtime.h>

#define N_NODES 10000
#define IN_DIM  256
#define OUT_DIM 64
#define ALPHA   0.2f
#define CAPS    128   // slot capacity/row (mean deg 32, max ~66; P(>128) ~ 1e-40, clamped)
#define NBG     625   // gemm blocks (625 x 16 rows = 10000)

typedef __attribute__((ext_vector_type(8))) short short8v;  // 8 bf16 (4 VGPRs)
typedef __attribute__((ext_vector_type(4))) float f32x4;    // 4 fp32 acc

__device__ __forceinline__ ushort f2bf(float f) {
    unsigned u = __float_as_uint(f);
    return (ushort)((u + 0x7FFFu + ((u >> 16) & 1u)) >> 16);   // RNE
}
__device__ __forceinline__ float bf2f(ushort u) {
    return __uint_as_float((unsigned)u << 16);
}

// ---------------------------------------------------------------------------
// Dispatch 0 (k_prep): zero cur[] + build bf16 W-fragment table Wf (32 KB,
// L2-resident). R11 lesson: runtime memset dispatch costs only ~3us (the 40us
// fills in the profile are harness poison fills, outside the timed graph) —
// this kernel replaces it at the same cost while also de-duplicating the
// per-block W staging (625x).
// Fragment order: elem j of Wf[((s*4+ct)*64 + g*16+li)] = W[32s+8g+j][16ct+li]
// -> same (g,j)->k map as the A-fragment (consistent k-permutation cancels).
// ---------------------------------------------------------------------------
__global__ __launch_bounds__(256) void k_prep(const float* __restrict__ W,
                                              int* __restrict__ cur,
                                              ushort* __restrict__ Wf) {
    const int gid = blockIdx.x * 256 + threadIdx.x;   // 40 blocks -> 10240 threads
    for (int i = gid; i < N_NODES; i += 10240) cur[i] = 0;
    for (int w = gid; w < IN_DIM * OUT_DIM; w += 10240) {
        int k = w >> 6, c = w & 63;
        int s = k >> 5, k5 = k & 31, g = k5 >> 3, j = k5 & 7;
        int ct = c >> 4, li = c & 15;
        Wf[(((s * 4 + ct) * 64) + (g * 16 + li)) * 8 + j] = f2bf(W[w]);
    }
}

// ---------------------------------------------------------------------------
// Dispatch 1 (fused, heterogeneous blocks):
//   blocks [0, 625): bf16-MFMA GEMM Wh=X@W (stored bf16) + scores es/ed.
//   blocks [625, 1250): edge scatter, 2 edges/thread, storing only dst (4B);
//     independent of the GEMM -> runs concurrently, cost hidden.
// Round-3 lesson: no grid.sync() fusion (69->240us). Rounds 5-7: fp32-VALU
// GEMM is latency-bound (30-46us); MFMA fixed it (R8). C/D layout
// m89-verified: col=lane&15, row=(lane>>4)*4+reg.
// ---------------------------------------------------------------------------
__global__ __launch_bounds__(256) void k_fused(const float* __restrict__ X,
                                               const ushort* __restrict__ Wf,
                                               const float* __restrict__ a,
                                               const int* __restrict__ src,
                                               const int* __restrict__ dst,
                                               int E,
                                               ushort* __restrict__ Whb,
                                               float* __restrict__ es,
                                               float* __restrict__ ed,
                                               int* __restrict__ cur,
                                               int* __restrict__ slots) {
    const int t = threadIdx.x;
    const int b = blockIdx.x;

    if (b >= NBG) {
        // ---- scatter role: two edges per thread ----
        int i0 = (b - NBG) * 512 + t;
#pragma unroll
        for (int u = 0; u < 2; ++u) {
            int i = i0 + u * 256;
            if (i < E) {
                int s = src[i], d = dst[i];
                int p = atomicAdd(&cur[s], 1);
                if (p < CAPS) slots[(size_t)s * CAPS + p] = d;
            }
        }
        return;
    }

    // ---- gemm role ----
    __shared__ float les[16], led[16];
    if (t < 16) { les[t] = 0.f; led[t] = 0.f; }
    __syncthreads();

    const int wave = t >> 6;          // col-tile ct
    const int lane = t & 63;
    const int g = lane >> 4, li = lane & 15;
    const int row0 = b * 16;          // 625 * 16 = 10000 exactly
    const float* __restrict__ xrow = X + (size_t)(row0 + li) * IN_DIM + g * 8;
    const short8v* __restrict__ Wfrag = (const short8v*)Wf;

    f32x4 acc = {0.f, 0.f, 0.f, 0.f};
#pragma unroll
    for (int s = 0; s < 8; ++s) {
        float4 xa = *(const float4*)(xrow + s * 32);
        float4 xb = *(const float4*)(xrow + s * 32 + 4);
        short8v af;
        af[0] = (short)f2bf(xa.x); af[1] = (short)f2bf(xa.y);
        af[2] = (short)f2bf(xa.z); af[3] = (short)f2bf(xa.w);
        af[4] = (short)f2bf(xb.x); af[5] = (short)f2bf(xb.y);
        af[6] = (short)f2bf(xb.z); af[7] = (short)f2bf(xb.w);
        short8v bfv = Wfrag[(s * 4 + wave) * 64 + lane];   // 16B coalesced, L2
        acc = __builtin_amdgcn_mfma_f32_16x16x32_bf16(af, bfv, acc, 0, 0, 0);
    }

    const int colC = wave * 16 + li;
    const float asrc = a[colC];
    const float adst = a[OUT_DIM + colC];
#pragma unroll
    for (int j = 0; j < 4; ++j) {
        int row = row0 + g * 4 + j;
        float v = acc[j];
        Whb[(size_t)row * OUT_DIM + colC] = f2bf(v);
        float se = v * asrc, sd = v * adst;
        se += __shfl_xor(se, 1, 64); sd += __shfl_xor(sd, 1, 64);
        se += __shfl_xor(se, 2, 64); sd += __shfl_xor(sd, 2, 64);
        se += __shfl_xor(se, 4, 64); sd += __shfl_xor(sd, 4, 64);
        se += __shfl_xor(se, 8, 64); sd += __shfl_xor(sd, 8, 64);
        if (li == 0) {
            atomicAdd(&les[g * 4 + j], se);
            atomicAdd(&led[g * 4 + j], sd);
        }
    }
    __syncthreads();
    if (t < 16) { es[row0 + t] = les[t]; ed[row0 + t] = led[t]; }
}

// ---------------------------------------------------------------------------
// Dispatch 2: one wave per row. e = leakyrelu(es[r]+ed[d]) computed here;
// O(deg) LDS-hash dedupe (atomicCAS; surviving duplicate arbitrary since
// duplicates carry identical e). PV pass: DUAL-HALF gathers — lane =
// (half h = lane>>5, colpair c = lane&31); half h handles edges i with
// i%2==h via ushort2 loads (one wave instruction covers TWO Wh rows,
// halving gather instructions); halves combined with shfl_xor(.,32);
// float2 coalesced store.
// ---------------------------------------------------------------------------
__global__ __launch_bounds__(64) void k_attn_slots(const int* __restrict__ cur,
                                                   const int* __restrict__ slots,
                                                   const float* __restrict__ es,
                                                   const float* __restrict__ ed,
                                                   const ushort* __restrict__ Whb,
                                                   float* __restrict__ out) {
    const int r = blockIdx.x;
    const int lane = threadIdx.x;
    int deg = cur[r];
    if (deg > CAPS) deg = CAPS;

    if (deg == 0) {
        // softmax of all-NEG_FILL row is uniform -> column mean of Wh
        float acc = 0.f;
        for (int j = 0; j < N_NODES; ++j) acc += bf2f(Whb[(size_t)j * OUT_DIM + lane]);
        out[(size_t)r * OUT_DIM + lane] = acc / (float)N_NODES;
        return;
    }

    __shared__ int   htab[256];
    __shared__ int   sdst[CAPS];
    __shared__ float sp[CAPS];

    for (int i = lane; i < 256; i += 64) htab[i] = -1;
    __syncthreads();

    const float er = es[r];

    // pass A: load dst, gather ed, leaky, hash-dedupe, track max
    float m = -INFINITY;
    for (int i = lane; i < deg; i += 64) {
        int d = slots[(size_t)r * CAPS + i];
        float e = er + ed[d];
        e = e > 0.f ? e : ALPHA * e;
        bool first = true;
        unsigned h = ((unsigned)d * 2654435761u) >> 24;
        while (true) {
            int prev = atomicCAS(&htab[h], -1, d);
            if (prev == -1) break;                    // inserted: first
            if (prev == d) { first = false; break; }  // duplicate
            h = (h + 1) & 255;
        }
        if (!first) e = -INFINITY;                    // exp() -> 0
        sdst[i] = d;
        sp[i] = e;
        m = fmaxf(m, e);
    }
#pragma unroll
    for (int o = 32; o > 0; o >>= 1) m = fmaxf(m, __shfl_xor(m, o, 64));
    __syncthreads();

    // pass B: exp + sum
    float ssum = 0.f;
    for (int i = lane; i < deg; i += 64) {
        float p = __expf(sp[i] - m);
        sp[i] = p;
        ssum += p;
    }
#pragma unroll
    for (int o = 32; o > 0; o >>= 1) ssum += __shfl_xor(ssum, o, 64);
    __syncthreads();

    // pass C: dual-half PV. half h2 takes edges i%2==h2; lane covers columns
    // (2c, 2c+1) via ushort2; 8 pairs (16 edges) in flight per batch.
    const int h2 = lane >> 5;
    const int c  = lane & 31;
    const ushort2* __restrict__ W2 = (const ushort2*)Whb;   // row stride 32
    float ax = 0.f, ay = 0.f;
    const int npairs = deg >> 1;
    int ip = 0;
    for (; ip + 8 <= npairs; ip += 8) {
        float p[8]; int q[8]; ushort2 w[8];
#pragma unroll
        for (int u = 0; u < 8; ++u) {
            int i = 2 * (ip + u) + h2;
            p[u] = sp[i]; q[u] = sdst[i];
        }
#pragma unroll
        for (int u = 0; u < 8; ++u) w[u] = W2[(size_t)q[u] * 32 + c];
#pragma unroll
        for (int u = 0; u < 8; ++u) {
            ax = fmaf(p[u], bf2f(w[u].x), ax);
            ay = fmaf(p[u], bf2f(w[u].y), ay);
        }
    }
    for (; ip < npairs; ++ip) {
        int i = 2 * ip + h2;
        float p = sp[i];
        ushort2 w = W2[(size_t)sdst[i] * 32 + c];
        ax = fmaf(p, bf2f(w.x), ax);
        ay = fmaf(p, bf2f(w.y), ay);
    }
    if ((deg & 1) && h2 == 0) {       // odd tail: half 0 only
        int i = deg - 1;
        float p = sp[i];
        ushort2 w = W2[(size_t)sdst[i] * 32 + c];
        ax = fmaf(p, bf2f(w.x), ax);
        ay = fmaf(p, bf2f(w.y), ay);
    }
    ax += __shfl_xor(ax, 32, 64);
    ay += __shfl_xor(ay, 32, 64);
    if (h2 == 0) {
        float inv = 1.f / ssum;
        ((float2*)out)[(size_t)r * 32 + c] = make_float2(ax * inv, ay * inv);
    }
}

// ---------------------------------------------------------------------------
// FALLBACK (ws too small for slots+Wf): R9-proven separate-kernel path with
// in-kernel W staging.
// ---------------------------------------------------------------------------
__global__ __launch_bounds__(256) void k_gemm_mfma(const float* __restrict__ X,
                                                   const float* __restrict__ W,
                                                   const float* __restrict__ a,
                                                   ushort* __restrict__ Whb,
                                                   float* __restrict__ es,
                                                   float* __restrict__ ed,
                                                   int* __restrict__ zero10k) {
    const int t = threadIdx.x;
    const int b = blockIdx.x;
    const int gid = b * 256 + t;
    if (gid < N_NODES) zero10k[gid] = 0;

    __shared__ short8v bfragv[8 * 4 * 64];
    __shared__ float les[16], led[16];
    for (int w = t; w < IN_DIM * OUT_DIM; w += 256) {
        int k = w >> 6, c = w & 63;
        int s = k >> 5, k5 = k & 31, g = k5 >> 3, j = k5 & 7;
        int ct = c >> 4, li = c & 15;
        ((ushort*)bfragv)[(((s * 4 + ct) * 64) + (g * 16 + li)) * 8 + j] = f2bf(W[w]);
    }
    if (t < 16) { les[t] = 0.f; led[t] = 0.f; }
    __syncthreads();

    const int wave = t >> 6, lane = t & 63;
    const int g = lane >> 4, li = lane & 15;
    const int row0 = b * 16;
    const float* __restrict__ xrow = X + (size_t)(row0 + li) * IN_DIM + g * 8;

    f32x4 acc = {0.f, 0.f, 0.f, 0.f};
#pragma unroll
    for (int s = 0; s < 8; ++s) {
        float4 xa = *(const float4*)(xrow + s * 32);
        float4 xb = *(const float4*)(xrow + s * 32 + 4);
        short8v af;
        af[0] = (short)f2bf(xa.x); af[1] = (short)f2bf(xa.y);
        af[2] = (short)f2bf(xa.z); af[3] = (short)f2bf(xa.w);
        af[4] = (short)f2bf(xb.x); af[5] = (short)f2bf(xb.y);
        af[6] = (short)f2bf(xb.z); af[7] = (short)f2bf(xb.w);
        short8v bfv = bfragv[(s * 4 + wave) * 64 + lane];
        acc = __builtin_amdgcn_mfma_f32_16x16x32_bf16(af, bfv, acc, 0, 0, 0);
    }
    const int colC = wave * 16 + li;
    const float asrc = a[colC];
    const float adst = a[OUT_DIM + colC];
#pragma unroll
    for (int j = 0; j < 4; ++j) {
        int row = row0 + g * 4 + j;
        float v = acc[j];
        Whb[(size_t)row * OUT_DIM + colC] = f2bf(v);
        float se = v * asrc, sd = v * adst;
        se += __shfl_xor(se, 1, 64); sd += __shfl_xor(sd, 1, 64);
        se += __shfl_xor(se, 2, 64); sd += __shfl_xor(sd, 2, 64);
        se += __shfl_xor(se, 4, 64); sd += __shfl_xor(sd, 4, 64);
        se += __shfl_xor(se, 8, 64); sd += __shfl_xor(sd, 8, 64);
        if (li == 0) { atomicAdd(&les[g * 4 + j], se); atomicAdd(&led[g * 4 + j], sd); }
    }
    __syncthreads();
    if (t < 16) { es[row0 + t] = les[t]; ed[row0 + t] = led[t]; }
}

__global__ void k_fill_slots(const int* __restrict__ src, const int* __restrict__ dst,
                             int E, int* __restrict__ cur, int* __restrict__ slots) {
    int i = blockIdx.x * 256 + threadIdx.x;
    if (i < E) {
        int s = src[i], d = dst[i];
        int p = atomicAdd(&cur[s], 1);
        if (p < CAPS) slots[(size_t)s * CAPS + p] = d;
    }
}

// ---------------------------------------------------------------------------
extern "C" void kernel_launch(void* const* d_in, const int* in_sizes, int n_in,
                              void* d_out, int out_size, void* d_ws, size_t ws_size,
                              hipStream_t stream) {
    const float* X     = (const float*)d_in[0];
    const int*   edges = (const int*)d_in[1];
    const float* W     = (const float*)d_in[2];
    const float* a     = (const float*)d_in[3];
    float* out = (float*)d_out;

    const int E = in_sizes[1] / 2;
    const int* src = edges;
    const int* dst = edges + E;

    char* ws = (char*)d_ws;
    size_t o = 0;
    auto carve = [&](size_t bytes) -> void* {
        o = (o + 255) & ~(size_t)255;
        void* p = ws + o;
        o += bytes;
        return p;
    };
    ushort* Whb   = (ushort*)carve((size_t)N_NODES * OUT_DIM * 2);
    float*  es    = (float*)carve((size_t)N_NODES * 4);
    float*  ed    = (float*)carve((size_t)N_NODES * 4);
    int*    cur   = (int*)carve((size_t)N_NODES * 4);
    int*    slots = (int*)carve((size_t)N_NODES * CAPS * 4);
    ushort* Wf    = (ushort*)carve((size_t)IN_DIM * OUT_DIM * 2);

    const int nsc = (E + 511) / 512;   // scatter blocks (2 edges/thread)

    if (o <= ws_size) {
        k_prep      <<<40, 256, 0, stream>>>(W, cur, Wf);
        k_fused     <<<NBG + nsc, 256, 0, stream>>>(X, Wf, a, src, dst, E,
                                                    Whb, es, ed, cur, slots);
        k_attn_slots<<<N_NODES, 64, 0, stream>>>(cur, slots, es, ed, Whb, out);
    } else {
        // fallback: R9-style separate kernels (gemm zeroes cur)
        k_gemm_mfma <<<NBG, 256, 0, stream>>>(X, W, a, Whb, es, ed, cur);
        k_fill_slots<<<(E + 255) / 256, 256, 0, stream>>>(src, dst, E, cur, slots);
        k_attn_slots<<<N_NODES, 64, 0, stream>>>(cur, slots, es, ed, Whb, out);
    }
}

// Round 13
// 42.270 us; speedup vs baseline: 1.9302x; 1.0594x over previous
//
#include <hip/hip_runtime.h>

#define N_NODES 10000
#define IN_DIM  256
#define OUT_DIM 64
#define ALPHA   0.2f
#define CAPS    128   // hash-slot capacity/row, pow2 (max distinct deg ~66 << 128)
#define NBG     625   // gemm blocks (625 x 16 rows = 10000)

typedef __attribute__((ext_vector_type(8))) short short8v;  // 8 bf16 (4 VGPRs)
typedef __attribute__((ext_vector_type(4))) float f32x4;    // 4 fp32 acc

__device__ __forceinline__ ushort f2bf(float f) {
    unsigned u = __float_as_uint(f);
    return (ushort)((u + 0x7FFFu + ((u >> 16) & 1u)) >> 16);   // RNE
}
__device__ __forceinline__ float bf2f(ushort u) {
    return __uint_as_float((unsigned)u << 16);
}

// ---------------------------------------------------------------------------
// Dispatch 0 (k_prep): clear the 5MB hash-slot table to -1 (int4 stores,
// HBM-BW bound ~1us) + build bf16 W-fragment table Wf (32 KB, L2-resident).
// R13: cur[] counter eliminated — scatter now dedupes via hash placement,
// so no zeroed counters are needed anywhere.
// Fragment order: elem j of Wf[((s*4+ct)*64 + g*16+li)] = W[32s+8g+j][16ct+li]
// -> same (g,j)->k map as the A-fragment (consistent k-permutation cancels).
// ---------------------------------------------------------------------------
__global__ __launch_bounds__(256) void k_prep(const float* __restrict__ W,
                                              int4* __restrict__ slots4,
                                              ushort* __restrict__ Wf) {
    const int gid = blockIdx.x * 256 + threadIdx.x;   // 256 blocks -> 65536 threads
    const int4 neg = make_int4(-1, -1, -1, -1);
    for (int i = gid; i < N_NODES * CAPS / 4; i += 65536) slots4[i] = neg;
    for (int w = gid; w < IN_DIM * OUT_DIM; w += 65536) {
        int k = w >> 6, c = w & 63;
        int s = k >> 5, k5 = k & 31, g = k5 >> 3, j = k5 & 7;
        int ct = c >> 4, li = c & 15;
        Wf[(((s * 4 + ct) * 64) + (g * 16 + li)) * 8 + j] = f2bf(W[w]);
    }
}

// ---------------------------------------------------------------------------
// Dispatch 1 (fused, heterogeneous blocks):
//   blocks [0, 625): bf16-MFMA GEMM Wh=X@W (stored bf16) + scores es/ed.
//   blocks [625, 1250): edge scatter, 2 edges/thread, HASH-PLACED into the
//     per-row slot table keyed by dst: atomicCAS(-1 -> d); prev==d means
//     duplicate (src,dst) pair -> dropped, matching reference .at[].set
//     counting each unique pair once. Runs concurrently with gemm blocks.
// Round-3 lesson: no grid.sync() fusion (69->240us). Rounds 5-7: fp32-VALU
// GEMM is latency-bound (30-46us); MFMA fixed it (R8). C/D layout
// m89-verified: col=lane&15, row=(lane>>4)*4+reg.
// ---------------------------------------------------------------------------
__global__ __launch_bounds__(256) void k_fused(const float* __restrict__ X,
                                               const ushort* __restrict__ Wf,
                                               const float* __restrict__ a,
                                               const int* __restrict__ src,
                                               const int* __restrict__ dst,
                                               int E,
                                               ushort* __restrict__ Whb,
                                               float* __restrict__ es,
                                               float* __restrict__ ed,
                                               int* __restrict__ slots) {
    const int t = threadIdx.x;
    const int b = blockIdx.x;

    if (b >= NBG) {
        // ---- scatter role: two edges per thread, hash-dedupe placement ----
        int i0 = (b - NBG) * 512 + t;
#pragma unroll
        for (int u = 0; u < 2; ++u) {
            int i = i0 + u * 256;
            if (i < E) {
                int s = src[i], d = dst[i];
                int* row = slots + (size_t)s * CAPS;
                unsigned h = ((unsigned)d * 2654435761u) >> 25;   // top 7 bits
                for (int it = 0; it < CAPS; ++it) {
                    int prev = atomicCAS(&row[h], -1, d);
                    if (prev == -1 || prev == d) break;   // placed, or duplicate
                    h = (h + 1) & (CAPS - 1);
                }
            }
        }
        return;
    }

    // ---- gemm role ----
    __shared__ float les[16], led[16];
    if (t < 16) { les[t] = 0.f; led[t] = 0.f; }
    __syncthreads();

    const int wave = t >> 6;          // col-tile ct
    const int lane = t & 63;
    const int g = lane >> 4, li = lane & 15;
    const int row0 = b * 16;          // 625 * 16 = 10000 exactly
    const float* __restrict__ xrow = X + (size_t)(row0 + li) * IN_DIM + g * 8;
    const short8v* __restrict__ Wfrag = (const short8v*)Wf;

    f32x4 acc = {0.f, 0.f, 0.f, 0.f};
#pragma unroll
    for (int s = 0; s < 8; ++s) {
        float4 xa = *(const float4*)(xrow + s * 32);
        float4 xb = *(const float4*)(xrow + s * 32 + 4);
        short8v af;
        af[0] = (short)f2bf(xa.x); af[1] = (short)f2bf(xa.y);
        af[2] = (short)f2bf(xa.z); af[3] = (short)f2bf(xa.w);
        af[4] = (short)f2bf(xb.x); af[5] = (short)f2bf(xb.y);
        af[6] = (short)f2bf(xb.z); af[7] = (short)f2bf(xb.w);
        short8v bfv = Wfrag[(s * 4 + wave) * 64 + lane];   // 16B coalesced, L2
        acc = __builtin_amdgcn_mfma_f32_16x16x32_bf16(af, bfv, acc, 0, 0, 0);
    }

    const int colC = wave * 16 + li;
    const float asrc = a[colC];
    const float adst = a[OUT_DIM + colC];
#pragma unroll
    for (int j = 0; j < 4; ++j) {
        int row = row0 + g * 4 + j;
        float v = acc[j];
        Whb[(size_t)row * OUT_DIM + colC] = f2bf(v);
        float se = v * asrc, sd = v * adst;
        se += __shfl_xor(se, 1, 64); sd += __shfl_xor(sd, 1, 64);
        se += __shfl_xor(se, 2, 64); sd += __shfl_xor(sd, 2, 64);
        se += __shfl_xor(se, 4, 64); sd += __shfl_xor(sd, 4, 64);
        se += __shfl_xor(se, 8, 64); sd += __shfl_xor(sd, 8, 64);
        if (li == 0) {
            atomicAdd(&les[g * 4 + j], se);
            atomicAdd(&led[g * 4 + j], sd);
        }
    }
    __syncthreads();
    if (t < 16) { es[row0 + t] = les[t]; ed[row0 + t] = led[t]; }
}

// ---------------------------------------------------------------------------
// Dispatch 2: one wave per row. Slots are pre-deduped -> no hash table, no
// CAS loop here. Each lane owns 2 slots; validity via ballot; softmax on
// registers; ballot/popc compaction into LDS; dual-half ushort2 PV gathers
// (one instruction covers two Wh rows); float2 coalesced store.
// ---------------------------------------------------------------------------
__global__ __launch_bounds__(64) void k_attn_hash(const int* __restrict__ slots,
                                                  const float* __restrict__ es,
                                                  const float* __restrict__ ed,
                                                  const ushort* __restrict__ Whb,
                                                  float* __restrict__ out) {
    const int r = blockIdx.x;
    const int lane = threadIdx.x;

    int d0 = slots[(size_t)r * CAPS + lane];
    int d1 = slots[(size_t)r * CAPS + 64 + lane];
    const bool v0 = d0 >= 0, v1 = d1 >= 0;
    const unsigned long long mask0 = __ballot(v0);
    const unsigned long long mask1 = __ballot(v1);

    if ((mask0 | mask1) == 0ull) {
        // row has no edges: softmax of all-NEG_FILL is uniform -> column mean
        float acc = 0.f;
        for (int j = 0; j < N_NODES; ++j) acc += bf2f(Whb[(size_t)j * OUT_DIM + lane]);
        out[(size_t)r * OUT_DIM + lane] = acc / (float)N_NODES;
        return;
    }

    const float er = es[r];
    float t0 = er + ed[v0 ? d0 : 0];  t0 = t0 > 0.f ? t0 : ALPHA * t0;
    float t1 = er + ed[v1 ? d1 : 0];  t1 = t1 > 0.f ? t1 : ALPHA * t1;
    float e0 = v0 ? t0 : -INFINITY;
    float e1 = v1 ? t1 : -INFINITY;

    float m = fmaxf(e0, e1);
#pragma unroll
    for (int o = 32; o > 0; o >>= 1) m = fmaxf(m, __shfl_xor(m, o, 64));

    float p0 = v0 ? __expf(e0 - m) : 0.f;
    float p1 = v1 ? __expf(e1 - m) : 0.f;
    float ssum = p0 + p1;
#pragma unroll
    for (int o = 32; o > 0; o >>= 1) ssum += __shfl_xor(ssum, o, 64);

    // ballot/popc compaction into LDS (dense [0,count) list)
    __shared__ int   sdst[CAPS];
    __shared__ float sp[CAPS];
    const unsigned long long below = (1ull << lane) - 1ull;
    const int cnt0 = __popcll(mask0);
    if (v0) {
        int p = __popcll(mask0 & below);
        sdst[p] = d0; sp[p] = p0;
    }
    if (v1) {
        int p = cnt0 + __popcll(mask1 & below);
        sdst[p] = d1; sp[p] = p1;
    }
    const int count = cnt0 + __popcll(mask1);
    __syncthreads();

    // dual-half PV: half h2 takes entries i%2==h2; lane covers columns
    // (2c, 2c+1) via ushort2; 8 pairs (16 entries) in flight per batch.
    const int h2 = lane >> 5;
    const int c  = lane & 31;
    const ushort2* __restrict__ W2 = (const ushort2*)Whb;   // row stride 32
    float ax = 0.f, ay = 0.f;
    const int npairs = count >> 1;
    int ip = 0;
    for (; ip + 8 <= npairs; ip += 8) {
        float p[8]; int q[8]; ushort2 w[8];
#pragma unroll
        for (int u = 0; u < 8; ++u) {
            int i = 2 * (ip + u) + h2;
            p[u] = sp[i]; q[u] = sdst[i];
        }
#pragma unroll
        for (int u = 0; u < 8; ++u) w[u] = W2[(size_t)q[u] * 32 + c];
#pragma unroll
        for (int u = 0; u < 8; ++u) {
            ax = fmaf(p[u], bf2f(w[u].x), ax);
            ay = fmaf(p[u], bf2f(w[u].y), ay);
        }
    }
    for (; ip < npairs; ++ip) {
        int i = 2 * ip + h2;
        float p = sp[i];
        ushort2 w = W2[(size_t)sdst[i] * 32 + c];
        ax = fmaf(p, bf2f(w.x), ax);
        ay = fmaf(p, bf2f(w.y), ay);
    }
    if ((count & 1) && h2 == 0) {     // odd tail: half 0 only
        int i = count - 1;
        float p = sp[i];
        ushort2 w = W2[(size_t)sdst[i] * 32 + c];
        ax = fmaf(p, bf2f(w.x), ax);
        ay = fmaf(p, bf2f(w.y), ay);
    }
    ax += __shfl_xor(ax, 32, 64);
    ay += __shfl_xor(ay, 32, 64);
    if (h2 == 0) {
        float inv = 1.f / ssum;
        ((float2*)out)[(size_t)r * 32 + c] = make_float2(ax * inv, ay * inv);
    }
}

// ---------------------------------------------------------------------------
extern "C" void kernel_launch(void* const* d_in, const int* in_sizes, int n_in,
                              void* d_out, int out_size, void* d_ws, size_t ws_size,
                              hipStream_t stream) {
    const float* X     = (const float*)d_in[0];
    const int*   edges = (const int*)d_in[1];
    const float* W     = (const float*)d_in[2];
    const float* a     = (const float*)d_in[3];
    float* out = (float*)d_out;

    const int E = in_sizes[1] / 2;
    const int* src = edges;
    const int* dst = edges + E;

    char* ws = (char*)d_ws;
    size_t o = 0;
    auto carve = [&](size_t bytes) -> void* {
        o = (o + 255) & ~(size_t)255;
        void* p = ws + o;
        o += bytes;
        return p;
    };
    ushort* Whb   = (ushort*)carve((size_t)N_NODES * OUT_DIM * 2);
    float*  es    = (float*)carve((size_t)N_NODES * 4);
    float*  ed    = (float*)carve((size_t)N_NODES * 4);
    int*    slots = (int*)carve((size_t)N_NODES * CAPS * 4);   // 16B-aligned (carve rounds to 256)
    ushort* Wf    = (ushort*)carve((size_t)IN_DIM * OUT_DIM * 2);

    const int nsc = (E + 511) / 512;   // scatter blocks (2 edges/thread) = 625

    // ~6.5 MB total; ws has always sufficed (12 rounds). All three kernels
    // are required in sequence: prep (clear slots + Wf) -> fused -> attn.
    k_prep     <<<256, 256, 0, stream>>>(W, (int4*)slots, Wf);
    k_fused    <<<NBG + nsc, 256, 0, stream>>>(X, Wf, a, src, dst, E,
                                               Whb, es, ed, slots);
    k_attn_hash<<<N_NODES, 64, 0, stream>>>(slots, es, ed, Whb, out);
}